// Round 12
// baseline (342.324 us; speedup 1.0000x reference)
//
#include <hip/hip_runtime.h>
#include <hip/hip_bf16.h>
#include <float.h>

// B=4, S=2048, D=1024 causal attention with input projections.
// out = softmax(mask((q@Wq)(k@Wk)^T / 32)) @ (v@Wv)
//
// Numerics: logits std ~342 -> q/k path uses bf16x2 (hi/lo RTN) split
// arithmetic, ~2^-18 effective. RTN mandatory (R2 lesson). v path bf16.
//
// R12: unified 128x128-tile BK=64 counted-vmcnt GEMM core (R10's proven
// schedule shrunk for occupancy): 64 KB LDS -> 2 blocks/CU resident (m114
// inter-block overlap, absent in R10/R11's 1/CU 256x256). Used for BOTH
// proj (K'=3072 = [Ah.Bh|Al.Bh|Ah.Bl], 48 tiles) and qk (K'=1536/half,
// 24 tiles, replacing the full-drain __syncthreads loop). Swizzle
// byte^=(row&7)<<4 both sides (R10-measured 0 conflicts). Last iteration
// drains vmcnt(0) (no in-flight loads at endpgm -> safe with successors).

typedef __attribute__((ext_vector_type(8))) short bf16x8;
typedef __attribute__((ext_vector_type(4))) float f32x4;

#define MFMA16 __builtin_amdgcn_mfma_f32_16x16x32_bf16

union U8 { bf16x8 v; unsigned w[4]; };

__device__ __forceinline__ ushort f2bf(float x) {
  union { float f; unsigned u; } v; v.f = x;
  unsigned r = v.u + 0x7fffu + ((v.u >> 16) & 1u);
  return (ushort)(r >> 16);
}
__device__ __forceinline__ float bf2f(ushort h) {
  union { unsigned u; float f; } v; v.u = ((unsigned)h) << 16;
  return v.f;
}
__device__ __forceinline__ void splitf(float x, ushort& hi, ushort& lo) {
  hi = f2bf(x);
  lo = f2bf(x - bf2f(hi));
}

__device__ __forceinline__ bf16x8 cvt8(const float* lp) {
  U8 H;
#pragma unroll
  for (int p = 0; p < 4; ++p) {
    const unsigned u0 = __float_as_uint(lp[2 * p]);
    const unsigned u1 = __float_as_uint(lp[2 * p + 1]);
    const unsigned r0 = (u0 + 0x7fffu + ((u0 >> 16) & 1u)) >> 16;
    const unsigned r1 = (u1 + 0x7fffu + ((u1 >> 16) & 1u)) & 0xffff0000u;
    H.w[p] = r0 | r1;
  }
  return H.v;
}

#define GLOAD16(gp, lp)                                                        \
  __builtin_amdgcn_global_load_lds(                                            \
      (const __attribute__((address_space(1))) void*)(gp),                     \
      (__attribute__((address_space(3))) void*)(lp), 16, 0, 0)

#define BARRIER() asm volatile("s_barrier" ::: "memory")
#define VMCNT8() asm volatile("s_waitcnt vmcnt(8)" ::: "memory")
#define VMCNT0() asm volatile("s_waitcnt vmcnt(0)" ::: "memory")

// bf16 slab 128 x 32 (8 KB, 8 chunks)
__device__ __forceinline__ void stage_bf16_32(const ushort* g, int pitch,
                                              ushort* lds, int w, int lane) {
#pragma unroll
  for (int i = 0; i < 2; ++i) {
    const int c = w * 2 + i;
    const int row = c * 16 + (lane >> 2);
    const int kp = (lane & 3) * 8;
    GLOAD16(g + (size_t)row * pitch + kp, lds + c * 512);
  }
}
// bf16 slab 128 x 64 (16 KB, 16 chunks)
__device__ __forceinline__ void stage_bf16_64(const ushort* g, int pitch,
                                              ushort* lds, int w, int lane) {
#pragma unroll
  for (int i = 0; i < 4; ++i) {
    const int c = w * 4 + i;
    const int row = c * 8 + (lane >> 3);
    const int kp = (lane & 7) * 8;
    GLOAD16(g + (size_t)row * pitch + kp, lds + c * 512);
  }
}
// bf16 slab 64 x 64 (8 KB, 8 chunks)
__device__ __forceinline__ void stage_bf16_64x64(const ushort* g, int pitch,
                                                 ushort* lds, int w, int lane) {
#pragma unroll
  for (int i = 0; i < 2; ++i) {
    const int c = w * 2 + i;
    const int row = c * 8 + (lane >> 3);
    const int kp = (lane & 7) * 8;
    GLOAD16(g + (size_t)row * pitch + kp, lds + c * 512);
  }
}
// fp32 slab 128 x 32 (16 KB, 16 chunks)
__device__ __forceinline__ void stage_f32_32(const float* g, int pitch,
                                             float* lds, int w, int lane) {
#pragma unroll
  for (int i = 0; i < 4; ++i) {
    const int c = w * 4 + i;
    const int row = c * 8 + (lane >> 3);
    const int kp = (lane & 7) * 4;
    GLOAD16(g + (size_t)row * pitch + kp, lds + c * 256);
  }
}

// ---------------------------------------------------------------------------
// Shared 128x128 BK=64 counted-vmcnt GEMM core. K' = NT*64 over 3 segments
// of TPS tiles each: seg0 = Ah.Bh, seg1 = Al.Bh, seg2 = Ah.Bl.
// Per tile: stage ALL of T+1 (8 loads/thread); vmcnt(8); barrier;
// 16 ds_read + 32 MFMA; barrier. Last tile: vmcnt(0) (full drain).
// A/B pitch 1024 elems. Swizzle byte^=(row&7)<<4 both sides.
// ---------------------------------------------------------------------------
template <int NT, int TPS>
__device__ __forceinline__ void gemm128(
    const ushort* __restrict__ Ah, const ushort* __restrict__ Al,
    const ushort* __restrict__ Bh, const ushort* __restrict__ Bl,
    ushort (*As)[8192], ushort (*Bs)[8192], f32x4 (&acc)[4][4], int t) {
  const int lane = t & 63, w = t >> 6;
  const int wm = w >> 1, wn = w & 1;
  const int lr = lane & 15, kg = lane >> 4;

  auto stage_tile = [&](int kt) {
    const int seg = kt / TPS;
    const int k0 = (kt % TPS) * 64;
    const int slot = kt & 1;
    const ushort* ga = (seg == 1) ? Al : Ah;
    const ushort* gb = (seg == 2) ? Bl : Bh;
#pragma unroll
    for (int i = 0; i < 4; ++i) {
      const int c = t + i * 256;
      const int row = c >> 3;
      const int lcb = ((c & 7) * 16) ^ ((row & 7) << 4);
      GLOAD16(ga + (size_t)row * 1024 + k0 + (lcb >> 1), As[slot] + c * 8);
    }
#pragma unroll
    for (int i = 0; i < 4; ++i) {
      const int c = t + i * 256;
      const int row = c >> 3;
      const int lcb = ((c & 7) * 16) ^ ((row & 7) << 4);
      GLOAD16(gb + (size_t)row * 1024 + k0 + (lcb >> 1), Bs[slot] + c * 8);
    }
  };

  stage_tile(0);
  for (int kt = 0; kt < NT; ++kt) {
    const int slot = kt & 1;
    if (kt + 1 < NT) {
      stage_tile(kt + 1);  // 8 loads stay in flight across both barriers
      VMCNT8();            // tile kt's 8 loads landed
    } else {
      VMCNT0();
    }
    BARRIER();
    bf16x8 Ar[4][2], Br[4][2];
#pragma unroll
    for (int m = 0; m < 4; ++m)
#pragma unroll
      for (int ks = 0; ks < 2; ++ks) {
        const int row = wm * 64 + m * 16 + lr;
        const int cb = (ks * 64 + kg * 16) ^ ((row & 7) << 4);
        Ar[m][ks] =
            *reinterpret_cast<const bf16x8*>(&As[slot][row * 64 + (cb >> 1)]);
      }
#pragma unroll
    for (int n = 0; n < 4; ++n)
#pragma unroll
      for (int ks = 0; ks < 2; ++ks) {
        const int col = wn * 64 + n * 16 + lr;
        const int cb = (ks * 64 + kg * 16) ^ ((col & 7) << 4);
        Br[n][ks] =
            *reinterpret_cast<const bf16x8*>(&Bs[slot][col * 64 + (cb >> 1)]);
      }
    __builtin_amdgcn_s_setprio(1);
#pragma unroll
    for (int m = 0; m < 4; ++m)
#pragma unroll
      for (int n = 0; n < 4; ++n)
#pragma unroll
        for (int ks = 0; ks < 2; ++ks)
          acc[m][n] = MFMA16(Ar[m][ks], Br[n][ks], acc[m][n], 0, 0, 0);
    __builtin_amdgcn_s_setprio(0);
    BARRIER();
  }
}

// ---------------------------------------------------------------------------
// Merged prepass: f < 3072 -> W transpose+convert; f >= 3072 -> q/k split.
// ---------------------------------------------------------------------------
__global__ __launch_bounds__(256) void wt_split(
    const float* __restrict__ q, const float* __restrict__ k,
    const float* __restrict__ W0, const float* __restrict__ W1,
    const float* __restrict__ W2, ushort* __restrict__ Th0,
    ushort* __restrict__ Tl0, ushort* __restrict__ Th1,
    ushort* __restrict__ Tl1, ushort* __restrict__ Th2,
    ushort* __restrict__ qh, ushort* __restrict__ ql,
    ushort* __restrict__ kh, ushort* __restrict__ kl) {
  __shared__ float t[32][33];
  const int f = blockIdx.x;
  if (f < 3072) {
    const int z = f >> 10, r10 = f & 1023;
    const int bx = r10 & 31, by = r10 >> 5;
    const float* W = z == 0 ? W0 : (z == 1 ? W1 : W2);
    ushort* Th = z == 0 ? Th0 : (z == 1 ? Th1 : Th2);
    ushort* Tl = z == 0 ? Tl0 : (z == 1 ? Tl1 : nullptr);
    const int r = threadIdx.x >> 3, c4 = (threadIdx.x & 7) * 4;
    const float4 x = *reinterpret_cast<const float4*>(
        &W[(size_t)(bx * 32 + r) * 1024 + by * 32 + c4]);
    t[r][c4] = x.x; t[r][c4 + 1] = x.y; t[r][c4 + 2] = x.z; t[r][c4 + 3] = x.w;
    __syncthreads();
    ushort h[4], l[4];
#pragma unroll
    for (int j = 0; j < 4; ++j) splitf(t[c4 + j][r], h[j], l[j]);
    const size_t o = (size_t)(by * 32 + r) * 1024 + bx * 32 + c4;
    *reinterpret_cast<ushort4*>(&Th[o]) = ushort4{h[0], h[1], h[2], h[3]};
    if (Tl)
      *reinterpret_cast<ushort4*>(&Tl[o]) = ushort4{l[0], l[1], l[2], l[3]};
  } else {
    const int fl = f - 3072;
    const float* X = (fl >> 11) ? k : q;
    ushort* H = (fl >> 11) ? kh : qh;
    ushort* L = (fl >> 11) ? kl : ql;
    const int n4 = 2097152;
    for (int i = (fl & 2047) * 256 + threadIdx.x; i < n4; i += 2048 * 256) {
      const float4 x = reinterpret_cast<const float4*>(X)[i];
      ushort h0, l0, h1, l1, h2, l2, h3, l3;
      splitf(x.x, h0, l0); splitf(x.y, h1, l1);
      splitf(x.z, h2, l2); splitf(x.w, h3, l3);
      reinterpret_cast<ushort4*>(H)[i] = ushort4{h0, h1, h2, h3};
      reinterpret_cast<ushort4*>(L)[i] = ushort4{l0, l1, l2, l3};
    }
  }
}

// ---------------------------------------------------------------------------
// proj: q1/k1 = [q|k] @ Wt^T via gemm128<48,16>. Grid 1024 flat, chunked
// XCD swizzle. Output hi/lo bf16 split.
// ---------------------------------------------------------------------------
__global__ __launch_bounds__(256) void proj_qk12(
    const ushort* __restrict__ qsh, const ushort* __restrict__ qsl,
    const ushort* __restrict__ ksh, const ushort* __restrict__ ksl,
    const ushort* __restrict__ Wqth, const ushort* __restrict__ Wqtl,
    const ushort* __restrict__ Wkth, const ushort* __restrict__ Wktl,
    ushort* __restrict__ q1hi, ushort* __restrict__ q1lo,
    ushort* __restrict__ k1hi, ushort* __restrict__ k1lo) {
  __shared__ ushort As[2][8192], Bs[2][8192];
  const int bid = blockIdx.x;
  const int fid = (bid & 7) * 128 + (bid >> 3);  // chunked over 8 XCDs
  const int z = fid >> 9;
  const int r = fid & 511;
  const int yt = r >> 3, xt = r & 7;
  const ushort* Ah = (z ? ksh : qsh) + (size_t)yt * 128 * 1024;
  const ushort* Al = (z ? ksl : qsl) + (size_t)yt * 128 * 1024;
  const ushort* Bh = (z ? Wkth : Wqth) + (size_t)xt * 128 * 1024;
  const ushort* Bl = (z ? Wktl : Wqtl) + (size_t)xt * 128 * 1024;
  ushort* Oh = z ? k1hi : q1hi;
  ushort* Ol = z ? k1lo : q1lo;
  const int t = threadIdx.x;
  f32x4 acc[4][4] = {};
  gemm128<48, 16>(Ah, Al, Bh, Bl, As, Bs, acc, t);

  const int lane = t & 63, w = t >> 6;
  const int wm = w >> 1, wn = w & 1;
  const int lr = lane & 15, kg = lane >> 4;
#pragma unroll
  for (int m = 0; m < 4; ++m)
#pragma unroll
    for (int n = 0; n < 4; ++n)
#pragma unroll
      for (int reg = 0; reg < 4; ++reg) {
        const int gm = yt * 128 + wm * 64 + m * 16 + kg * 4 + reg;
        const int gn = xt * 128 + wn * 64 + n * 16 + lr;
        ushort h, l;
        splitf(acc[m][n][reg], h, l);
        Oh[(size_t)gm * 1024 + gn] = h;
        Ol[(size_t)gm * 1024 + gn] = l;
      }
}

// ---------------------------------------------------------------------------
// QK^T via gemm128<24,8> (split-K halves of 512 -> K'=1536). Flat grid 1088,
// chunked XCD swizzle. Packed tile output. No masking (softmax handles).
// ---------------------------------------------------------------------------
__global__ __launch_bounds__(256) void qk12(
    const ushort* __restrict__ q1h, const ushort* __restrict__ q1l,
    const ushort* __restrict__ k1h, const ushort* __restrict__ k1l,
    float* __restrict__ scoresA, float* __restrict__ scoresB) {
  __shared__ ushort As[2][8192], Bs[2][8192];
  const int f = blockIdx.x;
  const int s = (f & 7) * 136 + (f >> 3);
  const int z = s / 544;
  const int rem = s % 544;
  const int b = rem / 136;
  int p = rem % 136, ti = 0, accp = 0;
  while (accp + ti + 1 <= p) { accp += ti + 1; ++ti; }
  const int tj = p - accp;
  const int kh0 = z * 512;
  const ushort* qh = q1h + ((size_t)b * 2048 + ti * 128) * 1024 + kh0;
  const ushort* ql = q1l + ((size_t)b * 2048 + ti * 128) * 1024 + kh0;
  const ushort* kh = k1h + ((size_t)b * 2048 + tj * 128) * 1024 + kh0;
  const ushort* kl = k1l + ((size_t)b * 2048 + tj * 128) * 1024 + kh0;
  const int t = threadIdx.x;
  f32x4 acc[4][4] = {};
  gemm128<24, 8>(qh, ql, kh, kl, As, Bs, acc, t);

  const int lane = t & 63, w = t >> 6;
  const int wm = w >> 1, wn = w & 1;
  const int lr = lane & 15, kg = lane >> 4;
  const float sc = 0.03125f;  // 1/sqrt(1024)
  float* st = (z ? scoresB : scoresA) + ((size_t)b * 136 + p) * 16384;
#pragma unroll
  for (int m = 0; m < 4; ++m)
#pragma unroll
    for (int n = 0; n < 4; ++n)
#pragma unroll
      for (int reg = 0; reg < 4; ++reg) {
        const int il = wm * 64 + m * 16 + kg * 4 + reg;
        const int jl = wn * 64 + n * 16 + lr;
        st[il * 128 + jl] = acc[m][n][reg] * sc;
      }
}

// ---------------------------------------------------------------------------
// Merged: f < 8192 -> row softmax; f >= 8192 -> proj_v.
// ---------------------------------------------------------------------------
__global__ __launch_bounds__(256) void sm_projv(
    float* __restrict__ scoresA, const float* __restrict__ scoresB,
    const ushort* __restrict__ Wvt, const float* __restrict__ V,
    ushort* __restrict__ v1t) {
  __shared__ __align__(16) char smem[24576];
  const int tid = threadIdx.x, lane = tid & 63, w = tid >> 6;
  const int fg = blockIdx.x;
  if (fg < 8192) {
    float* red = reinterpret_cast<float*>(smem);
    const int b = fg >> 11, r = fg & 2047;
    const int ti = r >> 7, rl = r & 127, ncol = (ti + 1) * 128;
    const int valid = r + 1;
    const size_t tbase = ((size_t)b * 136 + (ti * (ti + 1)) / 2) * 16384;
    float* srowA = scoresA + tbase;
    const float* srowB = scoresB + tbase;

    float vals[2][4];
    float mx = -FLT_MAX;
#pragma unroll
    for (int c = 0; c < 2; ++c) {
      const int j = tid * 4 + c * 1024;
      const size_t o = (size_t)(j >> 7) * 16384 + rl * 128 + (j & 127);
      const float4 a = *reinterpret_cast<const float4*>(srowA + o);
      const float4 bb = *reinterpret_cast<const float4*>(srowB + o);
      vals[c][0] = (j + 0 < valid) ? a.x + bb.x : -FLT_MAX;
      vals[c][1] = (j + 1 < valid) ? a.y + bb.y : -FLT_MAX;
      vals[c][2] = (j + 2 < valid) ? a.z + bb.z : -FLT_MAX;
      vals[c][3] = (j + 3 < valid) ? a.w + bb.w : -FLT_MAX;
      mx = fmaxf(mx, fmaxf(fmaxf(vals[c][0], vals[c][1]),
                           fmaxf(vals[c][2], vals[c][3])));
    }
#pragma unroll
    for (int o = 32; o; o >>= 1) mx = fmaxf(mx, __shfl_xor(mx, o));
    if (lane == 0) red[w] = mx;
    __syncthreads();
    mx = fmaxf(fmaxf(red[0], red[1]), fmaxf(red[2], red[3]));

    float ex[2][4];
    float sum = 0.f;
#pragma unroll
    for (int c = 0; c < 2; ++c)
#pragma unroll
      for (int e = 0; e < 4; ++e) {
        const int j = tid * 4 + c * 1024 + e;
        ex[c][e] = (j < valid) ? __expf(vals[c][e] - mx) : 0.f;
        sum += ex[c][e];
      }
#pragma unroll
    for (int o = 32; o; o >>= 1) sum += __shfl_xor(sum, o);
    if (lane == 0) red[4 + w] = sum;
    __syncthreads();
    sum = red[4] + red[5] + red[6] + red[7];
    const float inv = 1.f / sum;
#pragma unroll
    for (int c = 0; c < 2; ++c) {
      const int j = tid * 4 + c * 1024;
      if (j < ncol) {
        ushort* pt =
            reinterpret_cast<ushort*>(srowA + (size_t)(j >> 7) * 16384);
        ushort4 pw;
        pw.x = f2bf(ex[c][0] * inv); pw.y = f2bf(ex[c][1] * inv);
        pw.z = f2bf(ex[c][2] * inv); pw.w = f2bf(ex[c][3] * inv);
        *reinterpret_cast<ushort4*>(&pt[rl * 256 + (j & 127)]) = pw;
      }
    }
  } else {
    ushort* Ahs = reinterpret_cast<ushort*>(smem);
    float* Bs = reinterpret_cast<float*>(smem + 8192);
    const int f2 = fg - 8192;
    const int yb = (f2 >> 3) & 7;
    const int xb = (f2 & 7) + ((f2 >> 6) << 3);
    const int wr = w >> 1, wc = w & 1;
    const int lr = lane & 15, kg = lane >> 4;
    const int m0 = yb * 128;
    const int n0 = xb * 128;
    f32x4 acc[4][4] = {};

    for (int k0 = 0; k0 < 1024; k0 += 32) {
      stage_bf16_32(Wvt + (size_t)m0 * 1024 + k0, 1024, Ahs, w, lane);
      stage_f32_32(V + (size_t)n0 * 1024 + k0, 1024, Bs, w, lane);
      __syncthreads();
      bf16x8 ah[4], bh[4];
#pragma unroll
      for (int m = 0; m < 4; ++m)
        ah[m] = *reinterpret_cast<bf16x8*>(
            &Ahs[(wr * 64 + m * 16 + lr) * 32 + kg * 8]);
#pragma unroll
      for (int n = 0; n < 4; ++n)
        bh[n] = cvt8(&Bs[(wc * 64 + n * 16 + lr) * 32 + kg * 8]);
#pragma unroll
      for (int m = 0; m < 4; ++m)
#pragma unroll
        for (int n = 0; n < 4; ++n)
          acc[m][n] = MFMA16(ah[m], bh[n], acc[m][n], 0, 0, 0);
      __syncthreads();
    }
#pragma unroll
    for (int m = 0; m < 4; ++m)
#pragma unroll
      for (int n = 0; n < 4; ++n)
#pragma unroll
        for (int reg = 0; reg < 4; ++reg) {
          const int gm = m0 + wr * 64 + m * 16 + kg * 4 + reg;
          const int gn = n0 + wc * 64 + n * 16 + lr;
          const int b = gn >> 11, jj = gn & 2047;
          v1t[((size_t)b << 21) + (size_t)gm * 2048 + jj] = f2bf(acc[m][n][reg]);
        }
  }
}

// ---------------------------------------------------------------------------
// PV: out = P @ v1. 128x64 tile (1024 blocks, 4/CU), chunked XCD swizzle.
// ---------------------------------------------------------------------------
__global__ __launch_bounds__(256) void pv2(const float* __restrict__ scores,
                                           const ushort* __restrict__ v1t,
                                           float* __restrict__ out) {
  __shared__ ushort Ps[128 * 64], Vs[64 * 64];
  const int fl = blockIdx.x;
  const int s = (fl & 7) * 128 + (fl >> 3);
  const int b = s >> 8, rem = s & 255;
  const int ti = 15 - (rem >> 4);
  const int n0 = (rem & 15) * 64;
  const int tid = threadIdx.x, lane = tid & 63, w = tid >> 6;
  const int wr = w >> 1, wc = w & 1;
  const int lr = lane & 15, kg = lane >> 4;
  const int tri_ti = (ti * (ti + 1)) / 2;
  const ushort* vbase = v1t + ((size_t)b << 21) + (size_t)n0 * 2048;
  const int kend = (ti + 1) * 128;
  f32x4 acc[4][2] = {};

  for (int k0 = 0; k0 < kend; k0 += 64) {
    const ushort* pt = reinterpret_cast<const ushort*>(
        scores + ((size_t)b * 136 + tri_ti + (k0 >> 7)) * 16384);
    stage_bf16_64(pt + (k0 & 64), 256, Ps, w, lane);
    stage_bf16_64x64(vbase + k0, 2048, Vs, w, lane);
    __syncthreads();
#pragma unroll
    for (int t2 = 0; t2 < 2; ++t2) {
      bf16x8 pa[4], vb[2];
#pragma unroll
      for (int m = 0; m < 4; ++m)
        pa[m] = *reinterpret_cast<bf16x8*>(
            &Ps[(wr * 64 + m * 16 + lr) * 64 + t2 * 32 + kg * 8]);
#pragma unroll
      for (int n = 0; n < 2; ++n)
        vb[n] = *reinterpret_cast<bf16x8*>(
            &Vs[(wc * 32 + n * 16 + lr) * 64 + t2 * 32 + kg * 8]);
#pragma unroll
      for (int m = 0; m < 4; ++m)
#pragma unroll
        for (int n = 0; n < 2; ++n)
          acc[m][n] = MFMA16(pa[m], vb[n], acc[m][n], 0, 0, 0);
    }
    __syncthreads();
  }
#pragma unroll
  for (int m = 0; m < 4; ++m)
#pragma unroll
    for (int n = 0; n < 2; ++n)
#pragma unroll
      for (int reg = 0; reg < 4; ++reg) {
        const int gm = ti * 128 + wr * 64 + m * 16 + kg * 4 + reg;
        const int gn = n0 + wc * 32 + n * 16 + lr;
        out[((size_t)b * 2048 + gm) * 1024 + gn] = acc[m][n][reg];
      }
}

extern "C" void kernel_launch(void* const* d_in, const int* in_sizes, int n_in,
                              void* d_out, int out_size, void* d_ws,
                              size_t ws_size, hipStream_t stream) {
  const float* q = (const float*)d_in[0];
  const float* k = (const float*)d_in[1];
  const float* v = (const float*)d_in[2];
  const float* Wq = (const float*)d_in[4];
  const float* Wk = (const float*)d_in[5];
  const float* Wv = (const float*)d_in[6];
  float* out = (float*)d_out;

  char* ws = (char*)d_ws;
  const size_t SCORES_T = 35651584;  // 4*136*16384*4
  float* scoresA = (float*)ws;
  float* scoresB = (float*)(ws + SCORES_T);
  ushort* qsh = (ushort*)ws;
  ushort* qsl = qsh + 8388608;
  ushort* ksh = qsh + 2 * 8388608;
  ushort* ksl = qsh + 3 * 8388608;
  ushort* q1hi = (ushort*)(ws + 2 * SCORES_T);
  ushort* q1lo = q1hi + 8388608;
  ushort* k1hi = q1hi + 2 * 8388608;
  ushort* k1lo = q1hi + 3 * 8388608;
  ushort* v1t = (ushort*)(ws + 2 * SCORES_T);
  ushort* Wqth = (ushort*)(ws + 2 * SCORES_T + 67108864);
  ushort* Wqtl = Wqth + 1048576;
  ushort* Wkth = Wqth + 2097152;
  ushort* Wktl = Wqth + 3145728;
  ushort* Wvt  = Wqth + 4194304;
  const size_t need = 2 * SCORES_T + 67108864 + 10485760;
  if (ws_size < need) return;

  dim3 blk(256);
  wt_split<<<dim3(7168), blk, 0, stream>>>(q, k, Wq, Wk, Wv, Wqth, Wqtl, Wkth,
                                           Wktl, Wvt, qsh, qsl, ksh, ksl);
  proj_qk12<<<dim3(1024), blk, 0, stream>>>(qsh, qsl, ksh, ksl, Wqth, Wqtl,
                                            Wkth, Wktl, q1hi, q1lo, k1hi,
                                            k1lo);
  qk12<<<dim3(1088), blk, 0, stream>>>(q1hi, q1lo, k1hi, k1lo, scoresA,
                                       scoresB);
  sm_projv<<<dim3(8704), blk, 0, stream>>>(scoresA, scoresB, Wvt, v, v1t);
  pv2<<<dim3(1024), blk, 0, stream>>>(scoresA, v1t, out);
}

// Round 13
// 310.590 us; speedup vs baseline: 1.1022x; 1.1022x over previous
//
#include <hip/hip_runtime.h>
#include <hip/hip_bf16.h>
#include <float.h>

// B=4, S=2048, D=1024 causal attention with input projections.
// out = softmax(mask((q@Wq)(k@Wk)^T / 32)) @ (v@Wv)
//
// Numerics: logits std ~342 -> q/k path uses bf16x2 (hi/lo RTN) split
// arithmetic, ~2^-18 effective. RTN mandatory (R2 lesson). v path bf16.
//
// R13: revert to R10's proven best (256x256 counted-vmcnt proj at 940 TF,
// conflicts=0; full-drain qk2) after R11/R12 restructures regressed
// (8-phase null twice; 128x128 retile doubled stage:MFMA ratio).
// New: softmax causal load-guard (was reading full 2048-wide rows
// unconditionally -> ~64MB of the 136MB read was beyond the causal
// boundary; now guarded by j < ncol).

typedef __attribute__((ext_vector_type(8))) short bf16x8;
typedef __attribute__((ext_vector_type(4))) float f32x4;

#define MFMA16 __builtin_amdgcn_mfma_f32_16x16x32_bf16

union U8 { bf16x8 v; unsigned w[4]; };

__device__ __forceinline__ ushort f2bf(float x) {
  union { float f; unsigned u; } v; v.f = x;
  unsigned r = v.u + 0x7fffu + ((v.u >> 16) & 1u);
  return (ushort)(r >> 16);
}
__device__ __forceinline__ float bf2f(ushort h) {
  union { unsigned u; float f; } v; v.u = ((unsigned)h) << 16;
  return v.f;
}
__device__ __forceinline__ void splitf(float x, ushort& hi, ushort& lo) {
  hi = f2bf(x);
  lo = f2bf(x - bf2f(hi));
}

__device__ __forceinline__ bf16x8 cvt8(const float* lp) {
  U8 H;
#pragma unroll
  for (int p = 0; p < 4; ++p) {
    const unsigned u0 = __float_as_uint(lp[2 * p]);
    const unsigned u1 = __float_as_uint(lp[2 * p + 1]);
    const unsigned r0 = (u0 + 0x7fffu + ((u0 >> 16) & 1u)) >> 16;
    const unsigned r1 = (u1 + 0x7fffu + ((u1 >> 16) & 1u)) & 0xffff0000u;
    H.w[p] = r0 | r1;
  }
  return H.v;
}

#define GLOAD16(gp, lp)                                                        \
  __builtin_amdgcn_global_load_lds(                                            \
      (const __attribute__((address_space(1))) void*)(gp),                     \
      (__attribute__((address_space(3))) void*)(lp), 16, 0, 0)

#define BARRIER() asm volatile("s_barrier" ::: "memory")
#define VMCNT8() asm volatile("s_waitcnt vmcnt(8)" ::: "memory")

// bf16 slab 128 x 32 (8 KB, 8 chunks)
__device__ __forceinline__ void stage_bf16_32(const ushort* g, int pitch,
                                              ushort* lds, int w, int lane) {
#pragma unroll
  for (int i = 0; i < 2; ++i) {
    const int c = w * 2 + i;
    const int row = c * 16 + (lane >> 2);
    const int kp = (lane & 3) * 8;
    GLOAD16(g + (size_t)row * pitch + kp, lds + c * 512);
  }
}
// bf16 slab 128 x 64 (16 KB, 16 chunks)
__device__ __forceinline__ void stage_bf16_64(const ushort* g, int pitch,
                                              ushort* lds, int w, int lane) {
#pragma unroll
  for (int i = 0; i < 4; ++i) {
    const int c = w * 4 + i;
    const int row = c * 8 + (lane >> 3);
    const int kp = (lane & 7) * 8;
    GLOAD16(g + (size_t)row * pitch + kp, lds + c * 512);
  }
}
// bf16 slab 64 x 64 (8 KB, 8 chunks)
__device__ __forceinline__ void stage_bf16_64x64(const ushort* g, int pitch,
                                                 ushort* lds, int w, int lane) {
#pragma unroll
  for (int i = 0; i < 2; ++i) {
    const int c = w * 2 + i;
    const int row = c * 8 + (lane >> 3);
    const int kp = (lane & 7) * 8;
    GLOAD16(g + (size_t)row * pitch + kp, lds + c * 512);
  }
}
// fp32 slab 128 x 32 (16 KB, 16 chunks)
__device__ __forceinline__ void stage_f32_32(const float* g, int pitch,
                                             float* lds, int w, int lane) {
#pragma unroll
  for (int i = 0; i < 4; ++i) {
    const int c = w * 4 + i;
    const int row = c * 8 + (lane >> 3);
    const int kp = (lane & 7) * 4;
    GLOAD16(g + (size_t)row * pitch + kp, lds + c * 256);
  }
}

// Half-tile stage for proj_qk8: 128 rows x 64 cols bf16 (16 KB). Linear LDS
// dest; G4 swizzle byte ^= (row&7)<<4 realized by XORing the SOURCE column
// (rule #21: inverse-swz source + swz read, same involution).
__device__ __forceinline__ void stage_half8(const ushort* __restrict__ g,
                                            ushort* lds, int k0, int t) {
#pragma unroll
  for (int i = 0; i < 2; ++i) {
    const int c = t + i * 512;
    const int row = c >> 3;
    const int pcb = (c & 7) * 16;
    const int lcb = pcb ^ ((row & 7) << 4);
    GLOAD16(g + (size_t)row * 1024 + k0 + (lcb >> 1), lds + c * 8);
  }
}

// ---------------------------------------------------------------------------
// Merged prepass: f < 3072 -> W transpose+convert; f >= 3072 -> q/k split.
// ---------------------------------------------------------------------------
__global__ __launch_bounds__(256) void wt_split(
    const float* __restrict__ q, const float* __restrict__ k,
    const float* __restrict__ W0, const float* __restrict__ W1,
    const float* __restrict__ W2, ushort* __restrict__ Th0,
    ushort* __restrict__ Tl0, ushort* __restrict__ Th1,
    ushort* __restrict__ Tl1, ushort* __restrict__ Th2,
    ushort* __restrict__ qh, ushort* __restrict__ ql,
    ushort* __restrict__ kh, ushort* __restrict__ kl) {
  __shared__ float t[32][33];
  const int f = blockIdx.x;
  if (f < 3072) {
    const int z = f >> 10, r10 = f & 1023;
    const int bx = r10 & 31, by = r10 >> 5;
    const float* W = z == 0 ? W0 : (z == 1 ? W1 : W2);
    ushort* Th = z == 0 ? Th0 : (z == 1 ? Th1 : Th2);
    ushort* Tl = z == 0 ? Tl0 : (z == 1 ? Tl1 : nullptr);
    const int r = threadIdx.x >> 3, c4 = (threadIdx.x & 7) * 4;
    const float4 x = *reinterpret_cast<const float4*>(
        &W[(size_t)(bx * 32 + r) * 1024 + by * 32 + c4]);
    t[r][c4] = x.x; t[r][c4 + 1] = x.y; t[r][c4 + 2] = x.z; t[r][c4 + 3] = x.w;
    __syncthreads();
    ushort h[4], l[4];
#pragma unroll
    for (int j = 0; j < 4; ++j) splitf(t[c4 + j][r], h[j], l[j]);
    const size_t o = (size_t)(by * 32 + r) * 1024 + bx * 32 + c4;
    *reinterpret_cast<ushort4*>(&Th[o]) = ushort4{h[0], h[1], h[2], h[3]};
    if (Tl)
      *reinterpret_cast<ushort4*>(&Tl[o]) = ushort4{l[0], l[1], l[2], l[3]};
  } else {
    const int fl = f - 3072;
    const float* X = (fl >> 11) ? k : q;
    ushort* H = (fl >> 11) ? kh : qh;
    ushort* L = (fl >> 11) ? kl : ql;
    const int n4 = 2097152;
    for (int i = (fl & 2047) * 256 + threadIdx.x; i < n4; i += 2048 * 256) {
      const float4 x = reinterpret_cast<const float4*>(X)[i];
      ushort h0, l0, h1, l1, h2, l2, h3, l3;
      splitf(x.x, h0, l0); splitf(x.y, h1, l1);
      splitf(x.z, h2, l2); splitf(x.w, h3, l3);
      reinterpret_cast<ushort4*>(H)[i] = ushort4{h0, h1, h2, h3};
      reinterpret_cast<ushort4*>(L)[i] = ushort4{l0, l1, l2, l3};
    }
  }
}

// ---------------------------------------------------------------------------
// proj_qk8: O = A @ Wt^T as one bf16 GEMM, K' = 3072 segments
// [Ah.Bh | Al.Bh | Ah.Bl]. 256x256 tile, BK=64, 8 waves (2Mx4N).
// Per K-tile: stage ALL of tile T+1; vmcnt(8); barrier; body; barrier.
// 2 LDS slots (slot = kt&1, 128 KB). Grid 256, chunked XCD swizzle.
// (R10-proven: 109.7us, conflicts=0, ~940 TF.)
// ---------------------------------------------------------------------------
__global__ __launch_bounds__(512, 2) void proj_qk8(
    const ushort* __restrict__ Ah0, const ushort* __restrict__ Al0,
    const ushort* __restrict__ Ah1, const ushort* __restrict__ Al1,
    const ushort* __restrict__ Bh0, const ushort* __restrict__ Bl0,
    const ushort* __restrict__ Bh1, const ushort* __restrict__ Bl1,
    ushort* __restrict__ Oh0, ushort* __restrict__ Ol0,
    ushort* __restrict__ Oh1, ushort* __restrict__ Ol1) {
  __shared__ ushort As[2][16384];  // [slot][256 rows x 64 cols], 64 KB
  __shared__ ushort Bs[2][16384];  // 64 KB
  const int bid = blockIdx.x;
  const int fid = (bid & 7) * 32 + (bid >> 3);  // 256 blocks, 8 XCDs: chunked
  const int z = fid >> 7, r = fid & 127;
  const int yt = r >> 2, xt = r & 3;
  const ushort* Ah = z ? Ah1 : Ah0;
  const ushort* Al = z ? Al1 : Al0;
  const ushort* Bh = z ? Bh1 : Bh0;
  const ushort* Bl = z ? Bl1 : Bl0;
  ushort* Oh = z ? Oh1 : Oh0;
  ushort* Ol = z ? Ol1 : Ol0;
  const size_t am0 = (size_t)yt * 256 * 1024;
  const size_t bn0 = (size_t)xt * 256 * 1024;
  const int t = threadIdx.x;
  const int lane = t & 63, w = t >> 6;
  const int wm = w >> 2, wn = w & 3;
  const int lr = lane & 15, kg = lane >> 4;
  f32x4 acc[8][4] = {};
  bf16x8 Ar[4][2], Br[4][2];

  // Stage the FULL K-tile kt (4 units = 8 loads/thread).
  auto stage_tile = [&](int kt) {
    if (kt >= 48) kt -= 48;  // wrap: harmless dummy re-stage (uniform vmcnt)
    const int seg = kt >> 4;
    const int k0 = (kt & 15) * 64;
    const int slot = kt & 1;
    const ushort* ga = (seg == 1) ? Al : Ah;
    const ushort* gb = (seg == 2) ? Bl : Bh;
#pragma unroll
    for (int h = 0; h < 2; ++h)
      stage_half8(ga + am0 + (size_t)(h * 128) * 1024, &As[slot][h * 8192], k0, t);
#pragma unroll
    for (int h = 0; h < 2; ++h)
      stage_half8(gb + bn0 + (size_t)(h * 128) * 1024, &Bs[slot][h * 8192], k0, t);
  };
  auto loadA = [&](int slot, int mq) {
#pragma unroll
    for (int m = 0; m < 4; ++m)
#pragma unroll
      for (int ks = 0; ks < 2; ++ks) {
        const int row = wm * 128 + (mq * 4 + m) * 16 + lr;
        const int cb = (ks * 64 + kg * 16) ^ ((row & 7) << 4);
        Ar[m][ks] =
            *reinterpret_cast<const bf16x8*>(&As[slot][row * 64 + (cb >> 1)]);
      }
  };
  auto loadB = [&](int slot, int nq) {
#pragma unroll
    for (int n = 0; n < 2; ++n)
#pragma unroll
      for (int ks = 0; ks < 2; ++ks) {
        const int col = wn * 64 + (nq * 2 + n) * 16 + lr;
        const int cb = (ks * 64 + kg * 16) ^ ((col & 7) << 4);
        Br[nq * 2 + n][ks] =
            *reinterpret_cast<const bf16x8*>(&Bs[slot][col * 64 + (cb >> 1)]);
      }
  };
  auto mfma_q = [&](int mq, int nq) {
    __builtin_amdgcn_s_setprio(1);
#pragma unroll
    for (int m = 0; m < 4; ++m)
#pragma unroll
      for (int n = 0; n < 2; ++n)
#pragma unroll
        for (int ks = 0; ks < 2; ++ks)
          acc[mq * 4 + m][nq * 2 + n] = MFMA16(
              Ar[m][ks], Br[nq * 2 + n][ks], acc[mq * 4 + m][nq * 2 + n], 0, 0, 0);
    __builtin_amdgcn_s_setprio(0);
  };

  // Prologue: stage K-tile 0.
  stage_tile(0);
#pragma unroll 2
  for (int kt = 0; kt < 48; ++kt) {
    const int slot = kt & 1;
    stage_tile(kt + 1);   // 8 loads -> stay in flight across both barriers
    VMCNT8();             // drain only tile kt's 8 loads
    BARRIER();
    loadA(slot, 0); loadB(slot, 0);
    mfma_q(0, 0);
    loadB(slot, 1);
    mfma_q(0, 1);
    loadA(slot, 1);
    mfma_q(1, 0);
    mfma_q(1, 1);
    BARRIER();
  }

#pragma unroll
  for (int m = 0; m < 8; ++m)
#pragma unroll
    for (int n = 0; n < 4; ++n)
#pragma unroll
      for (int reg = 0; reg < 4; ++reg) {
        const int gm = yt * 256 + wm * 128 + m * 16 + kg * 4 + reg;
        const int gn = xt * 256 + wn * 64 + n * 16 + lr;
        ushort h, l;
        splitf(acc[m][n][reg], h, l);
        Oh[(size_t)gm * 1024 + gn] = h;
        Ol[(size_t)gm * 1024 + gn] = l;
      }
}

// ---------------------------------------------------------------------------
// QK^T, bf16x2 split (3 MFMA), causal triangular grid, SPLIT-K halves.
// Flat grid 1088, chunked XCD swizzle. Packed tile output. No masking.
// ---------------------------------------------------------------------------
__global__ __launch_bounds__(256) void qk2(
    const ushort* __restrict__ q1h, const ushort* __restrict__ q1l,
    const ushort* __restrict__ k1h, const ushort* __restrict__ k1l,
    float* __restrict__ scoresA, float* __restrict__ scoresB) {
  __shared__ ushort Ahs[4096], Als[4096], Bhs[4096], Bls[4096];
  const int f = blockIdx.x;
  const int s = (f & 7) * 136 + (f >> 3);
  const int z = s / 544;
  const int rem = s % 544;
  const int b = rem / 136;
  int p = rem % 136, ti = 0, accp = 0;
  while (accp + ti + 1 <= p) { accp += ti + 1; ++ti; }
  const int tj = p - accp;
  const int tid = threadIdx.x, lane = tid & 63, w = tid >> 6;
  const int wr = w >> 1, wc = w & 1;
  const int lr = lane & 15, kg = lane >> 4;
  const int kh0 = z * 512;
  const ushort* qh = q1h + ((size_t)b * 2048 + ti * 128) * 1024 + kh0;
  const ushort* ql = q1l + ((size_t)b * 2048 + ti * 128) * 1024 + kh0;
  const ushort* kh = k1h + ((size_t)b * 2048 + tj * 128) * 1024 + kh0;
  const ushort* kl = k1l + ((size_t)b * 2048 + tj * 128) * 1024 + kh0;
  f32x4 acc[4][4] = {};

  for (int k0 = 0; k0 < 512; k0 += 32) {
    stage_bf16_32(qh + k0, 1024, Ahs, w, lane);
    stage_bf16_32(ql + k0, 1024, Als, w, lane);
    stage_bf16_32(kh + k0, 1024, Bhs, w, lane);
    stage_bf16_32(kl + k0, 1024, Bls, w, lane);
    __syncthreads();
    bf16x8 ah[4], al[4], bh[4], bl[4];
#pragma unroll
    for (int m = 0; m < 4; ++m) {
      ah[m] = *reinterpret_cast<bf16x8*>(&Ahs[(wr * 64 + m * 16 + lr) * 32 + kg * 8]);
      al[m] = *reinterpret_cast<bf16x8*>(&Als[(wr * 64 + m * 16 + lr) * 32 + kg * 8]);
    }
#pragma unroll
    for (int n = 0; n < 4; ++n) {
      bh[n] = *reinterpret_cast<bf16x8*>(&Bhs[(wc * 64 + n * 16 + lr) * 32 + kg * 8]);
      bl[n] = *reinterpret_cast<bf16x8*>(&Bls[(wc * 64 + n * 16 + lr) * 32 + kg * 8]);
    }
#pragma unroll
    for (int m = 0; m < 4; ++m)
#pragma unroll
      for (int n = 0; n < 4; ++n) {
        acc[m][n] = MFMA16(ah[m], bh[n], acc[m][n], 0, 0, 0);
        acc[m][n] = MFMA16(ah[m], bl[n], acc[m][n], 0, 0, 0);
        acc[m][n] = MFMA16(al[m], bh[n], acc[m][n], 0, 0, 0);
      }
    __syncthreads();
  }
  const float sc = 0.03125f;
  float* st = (z ? scoresB : scoresA) + ((size_t)b * 136 + p) * 16384;
#pragma unroll
  for (int m = 0; m < 4; ++m)
#pragma unroll
    for (int n = 0; n < 4; ++n)
#pragma unroll
      for (int reg = 0; reg < 4; ++reg) {
        const int il = wr * 64 + m * 16 + kg * 4 + reg;
        const int jl = wc * 64 + n * 16 + lr;
        st[il * 128 + jl] = acc[m][n][reg] * sc;
      }
}

// ---------------------------------------------------------------------------
// Merged: f < 8192 -> row softmax (causal load-guard: only j < ncol loaded);
// f >= 8192 -> proj_v.
// ---------------------------------------------------------------------------
__global__ __launch_bounds__(256) void sm_projv(
    float* __restrict__ scoresA, const float* __restrict__ scoresB,
    const ushort* __restrict__ Wvt, const float* __restrict__ V,
    ushort* __restrict__ v1t) {
  __shared__ __align__(16) char smem[24576];
  const int tid = threadIdx.x, lane = tid & 63, w = tid >> 6;
  const int fg = blockIdx.x;
  if (fg < 8192) {
    float* red = reinterpret_cast<float*>(smem);
    const int b = fg >> 11, r = fg & 2047;
    const int ti = r >> 7, rl = r & 127, ncol = (ti + 1) * 128;
    const int valid = r + 1;
    const size_t tbase = ((size_t)b * 136 + (ti * (ti + 1)) / 2) * 16384;
    float* srowA = scoresA + tbase;
    const float* srowB = scoresB + tbase;

    float vals[2][4];
    float mx = -FLT_MAX;
#pragma unroll
    for (int c = 0; c < 2; ++c) {
      const int j = tid * 4 + c * 1024;
      if (j < ncol) {
        const size_t o = (size_t)(j >> 7) * 16384 + rl * 128 + (j & 127);
        const float4 a = *reinterpret_cast<const float4*>(srowA + o);
        const float4 bb = *reinterpret_cast<const float4*>(srowB + o);
        vals[c][0] = (j + 0 < valid) ? a.x + bb.x : -FLT_MAX;
        vals[c][1] = (j + 1 < valid) ? a.y + bb.y : -FLT_MAX;
        vals[c][2] = (j + 2 < valid) ? a.z + bb.z : -FLT_MAX;
        vals[c][3] = (j + 3 < valid) ? a.w + bb.w : -FLT_MAX;
      } else {
        vals[c][0] = vals[c][1] = vals[c][2] = vals[c][3] = -FLT_MAX;
      }
      mx = fmaxf(mx, fmaxf(fmaxf(vals[c][0], vals[c][1]),
                           fmaxf(vals[c][2], vals[c][3])));
    }
#pragma unroll
    for (int o = 32; o; o >>= 1) mx = fmaxf(mx, __shfl_xor(mx, o));
    if (lane == 0) red[w] = mx;
    __syncthreads();
    mx = fmaxf(fmaxf(red[0], red[1]), fmaxf(red[2], red[3]));

    float ex[2][4];
    float sum = 0.f;
#pragma unroll
    for (int c = 0; c < 2; ++c)
#pragma unroll
      for (int e = 0; e < 4; ++e) {
        const int j = tid * 4 + c * 1024 + e;
        ex[c][e] = (j < valid) ? __expf(vals[c][e] - mx) : 0.f;
        sum += ex[c][e];
      }
#pragma unroll
    for (int o = 32; o; o >>= 1) sum += __shfl_xor(sum, o);
    if (lane == 0) red[4 + w] = sum;
    __syncthreads();
    sum = red[4] + red[5] + red[6] + red[7];
    const float inv = 1.f / sum;
#pragma unroll
    for (int c = 0; c < 2; ++c) {
      const int j = tid * 4 + c * 1024;
      if (j < ncol) {
        ushort* pt =
            reinterpret_cast<ushort*>(srowA + (size_t)(j >> 7) * 16384);
        ushort4 pw;
        pw.x = f2bf(ex[c][0] * inv); pw.y = f2bf(ex[c][1] * inv);
        pw.z = f2bf(ex[c][2] * inv); pw.w = f2bf(ex[c][3] * inv);
        *reinterpret_cast<ushort4*>(&pt[rl * 256 + (j & 127)]) = pw;
      }
    }
  } else {
    ushort* Ahs = reinterpret_cast<ushort*>(smem);
    float* Bs = reinterpret_cast<float*>(smem + 8192);
    const int f2 = fg - 8192;
    const int yb = (f2 >> 3) & 7;
    const int xb = (f2 & 7) + ((f2 >> 6) << 3);
    const int wr = w >> 1, wc = w & 1;
    const int lr = lane & 15, kg = lane >> 4;
    const int m0 = yb * 128;
    const int n0 = xb * 128;
    f32x4 acc[4][4] = {};

    for (int k0 = 0; k0 < 1024; k0 += 32) {
      stage_bf16_32(Wvt + (size_t)m0 * 1024 + k0, 1024, Ahs, w, lane);
      stage_f32_32(V + (size_t)n0 * 1024 + k0, 1024, Bs, w, lane);
      __syncthreads();
      bf16x8 ah[4], bh[4];
#pragma unroll
      for (int m = 0; m < 4; ++m)
        ah[m] = *reinterpret_cast<bf16x8*>(
            &Ahs[(wr * 64 + m * 16 + lr) * 32 + kg * 8]);
#pragma unroll
      for (int n = 0; n < 4; ++n)
        bh[n] = cvt8(&Bs[(wc * 64 + n * 16 + lr) * 32 + kg * 8]);
#pragma unroll
      for (int m = 0; m < 4; ++m)
#pragma unroll
        for (int n = 0; n < 4; ++n)
          acc[m][n] = MFMA16(ah[m], bh[n], acc[m][n], 0, 0, 0);
      __syncthreads();
    }
#pragma unroll
    for (int m = 0; m < 4; ++m)
#pragma unroll
      for (int n = 0; n < 4; ++n)
#pragma unroll
        for (int reg = 0; reg < 4; ++reg) {
          const int gm = m0 + wr * 64 + m * 16 + kg * 4 + reg;
          const int gn = n0 + wc * 64 + n * 16 + lr;
          const int b = gn >> 11, jj = gn & 2047;
          v1t[((size_t)b << 21) + (size_t)gm * 2048 + jj] = f2bf(acc[m][n][reg]);
        }
  }
}

// ---------------------------------------------------------------------------
// PV: out = P @ v1. 128x64 tile (1024 blocks, 4/CU), chunked XCD swizzle.
// ---------------------------------------------------------------------------
__global__ __launch_bounds__(256) void pv2(const float* __restrict__ scores,
                                           const ushort* __restrict__ v1t,
                                           float* __restrict__ out) {
  __shared__ ushort Ps[128 * 64], Vs[64 * 64];
  const int fl = blockIdx.x;
  const int s = (fl & 7) * 128 + (fl >> 3);
  const int b = s >> 8, rem = s & 255;
  const int ti = 15 - (rem >> 4);
  const int n0 = (rem & 15) * 64;
  const int tid = threadIdx.x, lane = tid & 63, w = tid >> 6;
  const int wr = w >> 1, wc = w & 1;
  const int lr = lane & 15, kg = lane >> 4;
  const int tri_ti = (ti * (ti + 1)) / 2;
  const ushort* vbase = v1t + ((size_t)b << 21) + (size_t)n0 * 2048;
  const int kend = (ti + 1) * 128;
  f32x4 acc[4][2] = {};

  for (int k0 = 0; k0 < kend; k0 += 64) {
    const ushort* pt = reinterpret_cast<const ushort*>(
        scores + ((size_t)b * 136 + tri_ti + (k0 >> 7)) * 16384);
    stage_bf16_64(pt + (k0 & 64), 256, Ps, w, lane);
    stage_bf16_64x64(vbase + k0, 2048, Vs, w, lane);
    __syncthreads();
#pragma unroll
    for (int t2 = 0; t2 < 2; ++t2) {
      bf16x8 pa[4], vb[2];
#pragma unroll
      for (int m = 0; m < 4; ++m)
        pa[m] = *reinterpret_cast<bf16x8*>(
            &Ps[(wr * 64 + m * 16 + lr) * 64 + t2 * 32 + kg * 8]);
#pragma unroll
      for (int n = 0; n < 2; ++n)
        vb[n] = *reinterpret_cast<bf16x8*>(
            &Vs[(wc * 32 + n * 16 + lr) * 64 + t2 * 32 + kg * 8]);
#pragma unroll
      for (int m = 0; m < 4; ++m)
#pragma unroll
        for (int n = 0; n < 2; ++n)
          acc[m][n] = MFMA16(pa[m], vb[n], acc[m][n], 0, 0, 0);
    }
    __syncthreads();
  }
#pragma unroll
  for (int m = 0; m < 4; ++m)
#pragma unroll
    for (int n = 0; n < 2; ++n)
#pragma unroll
      for (int reg = 0; reg < 4; ++reg) {
        const int gm = ti * 128 + wr * 64 + m * 16 + kg * 4 + reg;
        const int gn = n0 + wc * 32 + n * 16 + lr;
        out[((size_t)b * 2048 + gm) * 1024 + gn] = acc[m][n][reg];
      }
}

extern "C" void kernel_launch(void* const* d_in, const int* in_sizes, int n_in,
                              void* d_out, int out_size, void* d_ws,
                              size_t ws_size, hipStream_t stream) {
  const float* q = (const float*)d_in[0];
  const float* k = (const float*)d_in[1];
  const float* v = (const float*)d_in[2];
  const float* Wq = (const float*)d_in[4];
  const float* Wk = (const float*)d_in[5];
  const float* Wv = (const float*)d_in[6];
  float* out = (float*)d_out;

  char* ws = (char*)d_ws;
  const size_t SCORES_T = 35651584;  // 4*136*16384*4
  float* scoresA = (float*)ws;
  float* scoresB = (float*)(ws + SCORES_T);
  ushort* qsh = (ushort*)ws;
  ushort* qsl = qsh + 8388608;
  ushort* ksh = qsh + 2 * 8388608;
  ushort* ksl = qsh + 3 * 8388608;
  ushort* q1hi = (ushort*)(ws + 2 * SCORES_T);
  ushort* q1lo = q1hi + 8388608;
  ushort* k1hi = q1hi + 2 * 8388608;
  ushort* k1lo = q1hi + 3 * 8388608;
  ushort* v1t = (ushort*)(ws + 2 * SCORES_T);
  ushort* Wqth = (ushort*)(ws + 2 * SCORES_T + 67108864);
  ushort* Wqtl = Wqth + 1048576;
  ushort* Wkth = Wqth + 2097152;
  ushort* Wktl = Wqth + 3145728;
  ushort* Wvt  = Wqth + 4194304;
  const size_t need = 2 * SCORES_T + 67108864 + 10485760;
  if (ws_size < need) return;

  dim3 blk(256);
  wt_split<<<dim3(7168), blk, 0, stream>>>(q, k, Wq, Wk, Wv, Wqth, Wqtl, Wkth,
                                           Wktl, Wvt, qsh, qsl, ksh, ksl);
  proj_qk8<<<dim3(256), dim3(512), 0, stream>>>(qsh, qsl, ksh, ksl, Wqth,
                                                Wqtl, Wkth, Wktl, q1hi, q1lo,
                                                k1hi, k1lo);
  qk2<<<dim3(1088), blk, 0, stream>>>(q1hi, q1lo, k1hi, k1lo, scoresA,
                                      scoresB);
  sm_projv<<<dim3(8704), blk, 0, stream>>>(scoresA, scoresB, Wvt, v, v1t);
  pv2<<<dim3(1024), blk, 0, stream>>>(scoresA, v1t, out);
}

// Round 14
// 301.634 us; speedup vs baseline: 1.1349x; 1.0297x over previous
//
#include <hip/hip_runtime.h>
#include <hip/hip_bf16.h>
#include <float.h>

// B=4, S=2048, D=1024 causal attention with input projections.
// out = softmax(mask((q@Wq)(k@Wk)^T / 32)) @ (v@Wv)
//
// Numerics: logits std ~342 -> q/k path uses bf16x2 (hi/lo RTN) split
// arithmetic, ~2^-18 effective. RTN mandatory (R2 lesson). v path bf16.
//
// R14: sm_projv block order flipped — the 512 long proj_v GEMM blocks now
// lead the grid (f < 512) so they start at t=0 and overlap the 8192 short
// softmax blocks, instead of waiting behind ~8 dispatch waves of them
// (duration was sum, becomes max). Everything else = R13 (R10-proven proj
// at 940 TF / conflicts=0; full-drain qk2; guarded softmax).

typedef __attribute__((ext_vector_type(8))) short bf16x8;
typedef __attribute__((ext_vector_type(4))) float f32x4;

#define MFMA16 __builtin_amdgcn_mfma_f32_16x16x32_bf16

union U8 { bf16x8 v; unsigned w[4]; };

__device__ __forceinline__ ushort f2bf(float x) {
  union { float f; unsigned u; } v; v.f = x;
  unsigned r = v.u + 0x7fffu + ((v.u >> 16) & 1u);
  return (ushort)(r >> 16);
}
__device__ __forceinline__ float bf2f(ushort h) {
  union { unsigned u; float f; } v; v.u = ((unsigned)h) << 16;
  return v.f;
}
__device__ __forceinline__ void splitf(float x, ushort& hi, ushort& lo) {
  hi = f2bf(x);
  lo = f2bf(x - bf2f(hi));
}

__device__ __forceinline__ bf16x8 cvt8(const float* lp) {
  U8 H;
#pragma unroll
  for (int p = 0; p < 4; ++p) {
    const unsigned u0 = __float_as_uint(lp[2 * p]);
    const unsigned u1 = __float_as_uint(lp[2 * p + 1]);
    const unsigned r0 = (u0 + 0x7fffu + ((u0 >> 16) & 1u)) >> 16;
    const unsigned r1 = (u1 + 0x7fffu + ((u1 >> 16) & 1u)) & 0xffff0000u;
    H.w[p] = r0 | r1;
  }
  return H.v;
}

#define GLOAD16(gp, lp)                                                        \
  __builtin_amdgcn_global_load_lds(                                            \
      (const __attribute__((address_space(1))) void*)(gp),                     \
      (__attribute__((address_space(3))) void*)(lp), 16, 0, 0)

#define BARRIER() asm volatile("s_barrier" ::: "memory")
#define VMCNT8() asm volatile("s_waitcnt vmcnt(8)" ::: "memory")

// bf16 slab 128 x 32 (8 KB, 8 chunks)
__device__ __forceinline__ void stage_bf16_32(const ushort* g, int pitch,
                                              ushort* lds, int w, int lane) {
#pragma unroll
  for (int i = 0; i < 2; ++i) {
    const int c = w * 2 + i;
    const int row = c * 16 + (lane >> 2);
    const int kp = (lane & 3) * 8;
    GLOAD16(g + (size_t)row * pitch + kp, lds + c * 512);
  }
}
// bf16 slab 128 x 64 (16 KB, 16 chunks)
__device__ __forceinline__ void stage_bf16_64(const ushort* g, int pitch,
                                              ushort* lds, int w, int lane) {
#pragma unroll
  for (int i = 0; i < 4; ++i) {
    const int c = w * 4 + i;
    const int row = c * 8 + (lane >> 3);
    const int kp = (lane & 7) * 8;
    GLOAD16(g + (size_t)row * pitch + kp, lds + c * 512);
  }
}
// bf16 slab 64 x 64 (8 KB, 8 chunks)
__device__ __forceinline__ void stage_bf16_64x64(const ushort* g, int pitch,
                                                 ushort* lds, int w, int lane) {
#pragma unroll
  for (int i = 0; i < 2; ++i) {
    const int c = w * 2 + i;
    const int row = c * 8 + (lane >> 3);
    const int kp = (lane & 7) * 8;
    GLOAD16(g + (size_t)row * pitch + kp, lds + c * 512);
  }
}
// fp32 slab 128 x 32 (16 KB, 16 chunks)
__device__ __forceinline__ void stage_f32_32(const float* g, int pitch,
                                             float* lds, int w, int lane) {
#pragma unroll
  for (int i = 0; i < 4; ++i) {
    const int c = w * 4 + i;
    const int row = c * 8 + (lane >> 3);
    const int kp = (lane & 7) * 4;
    GLOAD16(g + (size_t)row * pitch + kp, lds + c * 256);
  }
}

// Half-tile stage for proj_qk8: 128 rows x 64 cols bf16 (16 KB). Linear LDS
// dest; G4 swizzle byte ^= (row&7)<<4 realized by XORing the SOURCE column
// (rule #21: inverse-swz source + swz read, same involution).
__device__ __forceinline__ void stage_half8(const ushort* __restrict__ g,
                                            ushort* lds, int k0, int t) {
#pragma unroll
  for (int i = 0; i < 2; ++i) {
    const int c = t + i * 512;
    const int row = c >> 3;
    const int pcb = (c & 7) * 16;
    const int lcb = pcb ^ ((row & 7) << 4);
    GLOAD16(g + (size_t)row * 1024 + k0 + (lcb >> 1), lds + c * 8);
  }
}

// ---------------------------------------------------------------------------
// Merged prepass: f < 3072 -> W transpose+convert; f >= 3072 -> q/k split.
// ---------------------------------------------------------------------------
__global__ __launch_bounds__(256) void wt_split(
    const float* __restrict__ q, const float* __restrict__ k,
    const float* __restrict__ W0, const float* __restrict__ W1,
    const float* __restrict__ W2, ushort* __restrict__ Th0,
    ushort* __restrict__ Tl0, ushort* __restrict__ Th1,
    ushort* __restrict__ Tl1, ushort* __restrict__ Th2,
    ushort* __restrict__ qh, ushort* __restrict__ ql,
    ushort* __restrict__ kh, ushort* __restrict__ kl) {
  __shared__ float t[32][33];
  const int f = blockIdx.x;
  if (f < 3072) {
    const int z = f >> 10, r10 = f & 1023;
    const int bx = r10 & 31, by = r10 >> 5;
    const float* W = z == 0 ? W0 : (z == 1 ? W1 : W2);
    ushort* Th = z == 0 ? Th0 : (z == 1 ? Th1 : Th2);
    ushort* Tl = z == 0 ? Tl0 : (z == 1 ? Tl1 : nullptr);
    const int r = threadIdx.x >> 3, c4 = (threadIdx.x & 7) * 4;
    const float4 x = *reinterpret_cast<const float4*>(
        &W[(size_t)(bx * 32 + r) * 1024 + by * 32 + c4]);
    t[r][c4] = x.x; t[r][c4 + 1] = x.y; t[r][c4 + 2] = x.z; t[r][c4 + 3] = x.w;
    __syncthreads();
    ushort h[4], l[4];
#pragma unroll
    for (int j = 0; j < 4; ++j) splitf(t[c4 + j][r], h[j], l[j]);
    const size_t o = (size_t)(by * 32 + r) * 1024 + bx * 32 + c4;
    *reinterpret_cast<ushort4*>(&Th[o]) = ushort4{h[0], h[1], h[2], h[3]};
    if (Tl)
      *reinterpret_cast<ushort4*>(&Tl[o]) = ushort4{l[0], l[1], l[2], l[3]};
  } else {
    const int fl = f - 3072;
    const float* X = (fl >> 11) ? k : q;
    ushort* H = (fl >> 11) ? kh : qh;
    ushort* L = (fl >> 11) ? kl : ql;
    const int n4 = 2097152;
    for (int i = (fl & 2047) * 256 + threadIdx.x; i < n4; i += 2048 * 256) {
      const float4 x = reinterpret_cast<const float4*>(X)[i];
      ushort h0, l0, h1, l1, h2, l2, h3, l3;
      splitf(x.x, h0, l0); splitf(x.y, h1, l1);
      splitf(x.z, h2, l2); splitf(x.w, h3, l3);
      reinterpret_cast<ushort4*>(H)[i] = ushort4{h0, h1, h2, h3};
      reinterpret_cast<ushort4*>(L)[i] = ushort4{l0, l1, l2, l3};
    }
  }
}

// ---------------------------------------------------------------------------
// proj_qk8: O = A @ Wt^T as one bf16 GEMM, K' = 3072 segments
// [Ah.Bh | Al.Bh | Ah.Bl]. 256x256 tile, BK=64, 8 waves (2Mx4N).
// Per K-tile: stage ALL of tile T+1; vmcnt(8); barrier; body; barrier.
// 2 LDS slots (slot = kt&1, 128 KB). Grid 256, chunked XCD swizzle.
// (R10-proven: ~110us, conflicts=0, ~940 TF.)
// ---------------------------------------------------------------------------
__global__ __launch_bounds__(512, 2) void proj_qk8(
    const ushort* __restrict__ Ah0, const ushort* __restrict__ Al0,
    const ushort* __restrict__ Ah1, const ushort* __restrict__ Al1,
    const ushort* __restrict__ Bh0, const ushort* __restrict__ Bl0,
    const ushort* __restrict__ Bh1, const ushort* __restrict__ Bl1,
    ushort* __restrict__ Oh0, ushort* __restrict__ Ol0,
    ushort* __restrict__ Oh1, ushort* __restrict__ Ol1) {
  __shared__ ushort As[2][16384];  // [slot][256 rows x 64 cols], 64 KB
  __shared__ ushort Bs[2][16384];  // 64 KB
  const int bid = blockIdx.x;
  const int fid = (bid & 7) * 32 + (bid >> 3);  // 256 blocks, 8 XCDs: chunked
  const int z = fid >> 7, r = fid & 127;
  const int yt = r >> 2, xt = r & 3;
  const ushort* Ah = z ? Ah1 : Ah0;
  const ushort* Al = z ? Al1 : Al0;
  const ushort* Bh = z ? Bh1 : Bh0;
  const ushort* Bl = z ? Bl1 : Bl0;
  ushort* Oh = z ? Oh1 : Oh0;
  ushort* Ol = z ? Ol1 : Ol0;
  const size_t am0 = (size_t)yt * 256 * 1024;
  const size_t bn0 = (size_t)xt * 256 * 1024;
  const int t = threadIdx.x;
  const int lane = t & 63, w = t >> 6;
  const int wm = w >> 2, wn = w & 3;
  const int lr = lane & 15, kg = lane >> 4;
  f32x4 acc[8][4] = {};
  bf16x8 Ar[4][2], Br[4][2];

  // Stage the FULL K-tile kt (4 units = 8 loads/thread).
  auto stage_tile = [&](int kt) {
    if (kt >= 48) kt -= 48;  // wrap: harmless dummy re-stage (uniform vmcnt)
    const int seg = kt >> 4;
    const int k0 = (kt & 15) * 64;
    const int slot = kt & 1;
    const ushort* ga = (seg == 1) ? Al : Ah;
    const ushort* gb = (seg == 2) ? Bl : Bh;
#pragma unroll
    for (int h = 0; h < 2; ++h)
      stage_half8(ga + am0 + (size_t)(h * 128) * 1024, &As[slot][h * 8192], k0, t);
#pragma unroll
    for (int h = 0; h < 2; ++h)
      stage_half8(gb + bn0 + (size_t)(h * 128) * 1024, &Bs[slot][h * 8192], k0, t);
  };
  auto loadA = [&](int slot, int mq) {
#pragma unroll
    for (int m = 0; m < 4; ++m)
#pragma unroll
      for (int ks = 0; ks < 2; ++ks) {
        const int row = wm * 128 + (mq * 4 + m) * 16 + lr;
        const int cb = (ks * 64 + kg * 16) ^ ((row & 7) << 4);
        Ar[m][ks] =
            *reinterpret_cast<const bf16x8*>(&As[slot][row * 64 + (cb >> 1)]);
      }
  };
  auto loadB = [&](int slot, int nq) {
#pragma unroll
    for (int n = 0; n < 2; ++n)
#pragma unroll
      for (int ks = 0; ks < 2; ++ks) {
        const int col = wn * 64 + (nq * 2 + n) * 16 + lr;
        const int cb = (ks * 64 + kg * 16) ^ ((col & 7) << 4);
        Br[nq * 2 + n][ks] =
            *reinterpret_cast<const bf16x8*>(&Bs[slot][col * 64 + (cb >> 1)]);
      }
  };
  auto mfma_q = [&](int mq, int nq) {
    __builtin_amdgcn_s_setprio(1);
#pragma unroll
    for (int m = 0; m < 4; ++m)
#pragma unroll
      for (int n = 0; n < 2; ++n)
#pragma unroll
        for (int ks = 0; ks < 2; ++ks)
          acc[mq * 4 + m][nq * 2 + n] = MFMA16(
              Ar[m][ks], Br[nq * 2 + n][ks], acc[mq * 4 + m][nq * 2 + n], 0, 0, 0);
    __builtin_amdgcn_s_setprio(0);
  };

  // Prologue: stage K-tile 0.
  stage_tile(0);
#pragma unroll 2
  for (int kt = 0; kt < 48; ++kt) {
    const int slot = kt & 1;
    stage_tile(kt + 1);   // 8 loads -> stay in flight across both barriers
    VMCNT8();             // drain only tile kt's 8 loads
    BARRIER();
    loadA(slot, 0); loadB(slot, 0);
    mfma_q(0, 0);
    loadB(slot, 1);
    mfma_q(0, 1);
    loadA(slot, 1);
    mfma_q(1, 0);
    mfma_q(1, 1);
    BARRIER();
  }

#pragma unroll
  for (int m = 0; m < 8; ++m)
#pragma unroll
    for (int n = 0; n < 4; ++n)
#pragma unroll
      for (int reg = 0; reg < 4; ++reg) {
        const int gm = yt * 256 + wm * 128 + m * 16 + kg * 4 + reg;
        const int gn = xt * 256 + wn * 64 + n * 16 + lr;
        ushort h, l;
        splitf(acc[m][n][reg], h, l);
        Oh[(size_t)gm * 1024 + gn] = h;
        Ol[(size_t)gm * 1024 + gn] = l;
      }
}

// ---------------------------------------------------------------------------
// QK^T, bf16x2 split (3 MFMA), causal triangular grid, SPLIT-K halves.
// Flat grid 1088, chunked XCD swizzle. Packed tile output. No masking.
// ---------------------------------------------------------------------------
__global__ __launch_bounds__(256) void qk2(
    const ushort* __restrict__ q1h, const ushort* __restrict__ q1l,
    const ushort* __restrict__ k1h, const ushort* __restrict__ k1l,
    float* __restrict__ scoresA, float* __restrict__ scoresB) {
  __shared__ ushort Ahs[4096], Als[4096], Bhs[4096], Bls[4096];
  const int f = blockIdx.x;
  const int s = (f & 7) * 136 + (f >> 3);
  const int z = s / 544;
  const int rem = s % 544;
  const int b = rem / 136;
  int p = rem % 136, ti = 0, accp = 0;
  while (accp + ti + 1 <= p) { accp += ti + 1; ++ti; }
  const int tj = p - accp;
  const int tid = threadIdx.x, lane = tid & 63, w = tid >> 6;
  const int wr = w >> 1, wc = w & 1;
  const int lr = lane & 15, kg = lane >> 4;
  const int kh0 = z * 512;
  const ushort* qh = q1h + ((size_t)b * 2048 + ti * 128) * 1024 + kh0;
  const ushort* ql = q1l + ((size_t)b * 2048 + ti * 128) * 1024 + kh0;
  const ushort* kh = k1h + ((size_t)b * 2048 + tj * 128) * 1024 + kh0;
  const ushort* kl = k1l + ((size_t)b * 2048 + tj * 128) * 1024 + kh0;
  f32x4 acc[4][4] = {};

  for (int k0 = 0; k0 < 512; k0 += 32) {
    stage_bf16_32(qh + k0, 1024, Ahs, w, lane);
    stage_bf16_32(ql + k0, 1024, Als, w, lane);
    stage_bf16_32(kh + k0, 1024, Bhs, w, lane);
    stage_bf16_32(kl + k0, 1024, Bls, w, lane);
    __syncthreads();
    bf16x8 ah[4], al[4], bh[4], bl[4];
#pragma unroll
    for (int m = 0; m < 4; ++m) {
      ah[m] = *reinterpret_cast<bf16x8*>(&Ahs[(wr * 64 + m * 16 + lr) * 32 + kg * 8]);
      al[m] = *reinterpret_cast<bf16x8*>(&Als[(wr * 64 + m * 16 + lr) * 32 + kg * 8]);
    }
#pragma unroll
    for (int n = 0; n < 4; ++n) {
      bh[n] = *reinterpret_cast<bf16x8*>(&Bhs[(wc * 64 + n * 16 + lr) * 32 + kg * 8]);
      bl[n] = *reinterpret_cast<bf16x8*>(&Bls[(wc * 64 + n * 16 + lr) * 32 + kg * 8]);
    }
#pragma unroll
    for (int m = 0; m < 4; ++m)
#pragma unroll
      for (int n = 0; n < 4; ++n) {
        acc[m][n] = MFMA16(ah[m], bh[n], acc[m][n], 0, 0, 0);
        acc[m][n] = MFMA16(ah[m], bl[n], acc[m][n], 0, 0, 0);
        acc[m][n] = MFMA16(al[m], bh[n], acc[m][n], 0, 0, 0);
      }
    __syncthreads();
  }
  const float sc = 0.03125f;
  float* st = (z ? scoresB : scoresA) + ((size_t)b * 136 + p) * 16384;
#pragma unroll
  for (int m = 0; m < 4; ++m)
#pragma unroll
    for (int n = 0; n < 4; ++n)
#pragma unroll
      for (int reg = 0; reg < 4; ++reg) {
        const int il = wr * 64 + m * 16 + kg * 4 + reg;
        const int jl = wc * 64 + n * 16 + lr;
        st[il * 128 + jl] = acc[m][n][reg] * sc;
      }
}

// ---------------------------------------------------------------------------
// Merged: f < 512 -> proj_v (long GEMM blocks FIRST so they overlap the
// softmax tail instead of waiting behind it); f >= 512 -> row softmax
// (causal load-guard: only j < ncol loaded).
// ---------------------------------------------------------------------------
__global__ __launch_bounds__(256) void sm_projv(
    float* __restrict__ scoresA, const float* __restrict__ scoresB,
    const ushort* __restrict__ Wvt, const float* __restrict__ V,
    ushort* __restrict__ v1t) {
  __shared__ __align__(16) char smem[24576];
  const int tid = threadIdx.x, lane = tid & 63, w = tid >> 6;
  const int fg = blockIdx.x;
  if (fg >= 512) {
    float* red = reinterpret_cast<float*>(smem);
    const int f2 = fg - 512;
    const int b = f2 >> 11, r = f2 & 2047;
    const int ti = r >> 7, rl = r & 127, ncol = (ti + 1) * 128;
    const int valid = r + 1;
    const size_t tbase = ((size_t)b * 136 + (ti * (ti + 1)) / 2) * 16384;
    float* srowA = scoresA + tbase;
    const float* srowB = scoresB + tbase;

    float vals[2][4];
    float mx = -FLT_MAX;
#pragma unroll
    for (int c = 0; c < 2; ++c) {
      const int j = tid * 4 + c * 1024;
      if (j < ncol) {
        const size_t o = (size_t)(j >> 7) * 16384 + rl * 128 + (j & 127);
        const float4 a = *reinterpret_cast<const float4*>(srowA + o);
        const float4 bb = *reinterpret_cast<const float4*>(srowB + o);
        vals[c][0] = (j + 0 < valid) ? a.x + bb.x : -FLT_MAX;
        vals[c][1] = (j + 1 < valid) ? a.y + bb.y : -FLT_MAX;
        vals[c][2] = (j + 2 < valid) ? a.z + bb.z : -FLT_MAX;
        vals[c][3] = (j + 3 < valid) ? a.w + bb.w : -FLT_MAX;
      } else {
        vals[c][0] = vals[c][1] = vals[c][2] = vals[c][3] = -FLT_MAX;
      }
      mx = fmaxf(mx, fmaxf(fmaxf(vals[c][0], vals[c][1]),
                           fmaxf(vals[c][2], vals[c][3])));
    }
#pragma unroll
    for (int o = 32; o; o >>= 1) mx = fmaxf(mx, __shfl_xor(mx, o));
    if (lane == 0) red[w] = mx;
    __syncthreads();
    mx = fmaxf(fmaxf(red[0], red[1]), fmaxf(red[2], red[3]));

    float ex[2][4];
    float sum = 0.f;
#pragma unroll
    for (int c = 0; c < 2; ++c)
#pragma unroll
      for (int e = 0; e < 4; ++e) {
        const int j = tid * 4 + c * 1024 + e;
        ex[c][e] = (j < valid) ? __expf(vals[c][e] - mx) : 0.f;
        sum += ex[c][e];
      }
#pragma unroll
    for (int o = 32; o; o >>= 1) sum += __shfl_xor(sum, o);
    if (lane == 0) red[4 + w] = sum;
    __syncthreads();
    sum = red[4] + red[5] + red[6] + red[7];
    const float inv = 1.f / sum;
#pragma unroll
    for (int c = 0; c < 2; ++c) {
      const int j = tid * 4 + c * 1024;
      if (j < ncol) {
        ushort* pt =
            reinterpret_cast<ushort*>(srowA + (size_t)(j >> 7) * 16384);
        ushort4 pw;
        pw.x = f2bf(ex[c][0] * inv); pw.y = f2bf(ex[c][1] * inv);
        pw.z = f2bf(ex[c][2] * inv); pw.w = f2bf(ex[c][3] * inv);
        *reinterpret_cast<ushort4*>(&pt[rl * 256 + (j & 127)]) = pw;
      }
    }
  } else {
    ushort* Ahs = reinterpret_cast<ushort*>(smem);
    float* Bs = reinterpret_cast<float*>(smem + 8192);
    const int f2 = fg;
    const int yb = (f2 >> 3) & 7;
    const int xb = (f2 & 7) + ((f2 >> 6) << 3);
    const int wr = w >> 1, wc = w & 1;
    const int lr = lane & 15, kg = lane >> 4;
    const int m0 = yb * 128;
    const int n0 = xb * 128;
    f32x4 acc[4][4] = {};

    for (int k0 = 0; k0 < 1024; k0 += 32) {
      stage_bf16_32(Wvt + (size_t)m0 * 1024 + k0, 1024, Ahs, w, lane);
      stage_f32_32(V + (size_t)n0 * 1024 + k0, 1024, Bs, w, lane);
      __syncthreads();
      bf16x8 ah[4], bh[4];
#pragma unroll
      for (int m = 0; m < 4; ++m)
        ah[m] = *reinterpret_cast<bf16x8*>(
            &Ahs[(wr * 64 + m * 16 + lr) * 32 + kg * 8]);
#pragma unroll
      for (int n = 0; n < 4; ++n)
        bh[n] = cvt8(&Bs[(wc * 64 + n * 16 + lr) * 32 + kg * 8]);
#pragma unroll
      for (int m = 0; m < 4; ++m)
#pragma unroll
        for (int n = 0; n < 4; ++n)
          acc[m][n] = MFMA16(ah[m], bh[n], acc[m][n], 0, 0, 0);
      __syncthreads();
    }
#pragma unroll
    for (int m = 0; m < 4; ++m)
#pragma unroll
      for (int n = 0; n < 4; ++n)
#pragma unroll
        for (int reg = 0; reg < 4; ++reg) {
          const int gm = m0 + wr * 64 + m * 16 + kg * 4 + reg;
          const int gn = n0 + wc * 64 + n * 16 + lr;
          const int b = gn >> 11, jj = gn & 2047;
          v1t[((size_t)b << 21) + (size_t)gm * 2048 + jj] = f2bf(acc[m][n][reg]);
        }
  }
}

// ---------------------------------------------------------------------------
// PV: out = P @ v1. 128x64 tile (1024 blocks, 4/CU), chunked XCD swizzle.
// ---------------------------------------------------------------------------
__global__ __launch_bounds__(256) void pv2(const float* __restrict__ scores,
                                           const ushort* __restrict__ v1t,
                                           float* __restrict__ out) {
  __shared__ ushort Ps[128 * 64], Vs[64 * 64];
  const int fl = blockIdx.x;
  const int s = (fl & 7) * 128 + (fl >> 3);
  const int b = s >> 8, rem = s & 255;
  const int ti = 15 - (rem >> 4);
  const int n0 = (rem & 15) * 64;
  const int tid = threadIdx.x, lane = tid & 63, w = tid >> 6;
  const int wr = w >> 1, wc = w & 1;
  const int lr = lane & 15, kg = lane >> 4;
  const int tri_ti = (ti * (ti + 1)) / 2;
  const ushort* vbase = v1t + ((size_t)b << 21) + (size_t)n0 * 2048;
  const int kend = (ti + 1) * 128;
  f32x4 acc[4][2] = {};

  for (int k0 = 0; k0 < kend; k0 += 64) {
    const ushort* pt = reinterpret_cast<const ushort*>(
        scores + ((size_t)b * 136 + tri_ti + (k0 >> 7)) * 16384);
    stage_bf16_64(pt + (k0 & 64), 256, Ps, w, lane);
    stage_bf16_64x64(vbase + k0, 2048, Vs, w, lane);
    __syncthreads();
#pragma unroll
    for (int t2 = 0; t2 < 2; ++t2) {
      bf16x8 pa[4], vb[2];
#pragma unroll
      for (int m = 0; m < 4; ++m)
        pa[m] = *reinterpret_cast<bf16x8*>(
            &Ps[(wr * 64 + m * 16 + lr) * 64 + t2 * 32 + kg * 8]);
#pragma unroll
      for (int n = 0; n < 2; ++n)
        vb[n] = *reinterpret_cast<bf16x8*>(
            &Vs[(wc * 32 + n * 16 + lr) * 64 + t2 * 32 + kg * 8]);
#pragma unroll
      for (int m = 0; m < 4; ++m)
#pragma unroll
        for (int n = 0; n < 2; ++n)
          acc[m][n] = MFMA16(pa[m], vb[n], acc[m][n], 0, 0, 0);
    }
    __syncthreads();
  }
#pragma unroll
  for (int m = 0; m < 4; ++m)
#pragma unroll
    for (int n = 0; n < 2; ++n)
#pragma unroll
      for (int reg = 0; reg < 4; ++reg) {
        const int gm = ti * 128 + wr * 64 + m * 16 + kg * 4 + reg;
        const int gn = n0 + wc * 32 + n * 16 + lr;
        out[((size_t)b * 2048 + gm) * 1024 + gn] = acc[m][n][reg];
      }
}

extern "C" void kernel_launch(void* const* d_in, const int* in_sizes, int n_in,
                              void* d_out, int out_size, void* d_ws,
                              size_t ws_size, hipStream_t stream) {
  const float* q = (const float*)d_in[0];
  const float* k = (const float*)d_in[1];
  const float* v = (const float*)d_in[2];
  const float* Wq = (const float*)d_in[4];
  const float* Wk = (const float*)d_in[5];
  const float* Wv = (const float*)d_in[6];
  float* out = (float*)d_out;

  char* ws = (char*)d_ws;
  const size_t SCORES_T = 35651584;  // 4*136*16384*4
  float* scoresA = (float*)ws;
  float* scoresB = (float*)(ws + SCORES_T);
  ushort* qsh = (ushort*)ws;
  ushort* qsl = qsh + 8388608;
  ushort* ksh = qsh + 2 * 8388608;
  ushort* ksl = qsh + 3 * 8388608;
  ushort* q1hi = (ushort*)(ws + 2 * SCORES_T);
  ushort* q1lo = q1hi + 8388608;
  ushort* k1hi = q1hi + 2 * 8388608;
  ushort* k1lo = q1hi + 3 * 8388608;
  ushort* v1t = (ushort*)(ws + 2 * SCORES_T);
  ushort* Wqth = (ushort*)(ws + 2 * SCORES_T + 67108864);
  ushort* Wqtl = Wqth + 1048576;
  ushort* Wkth = Wqth + 2097152;
  ushort* Wktl = Wqth + 3145728;
  ushort* Wvt  = Wqth + 4194304;
  const size_t need = 2 * SCORES_T + 67108864 + 10485760;
  if (ws_size < need) return;

  dim3 blk(256);
  wt_split<<<dim3(7168), blk, 0, stream>>>(q, k, Wq, Wk, Wv, Wqth, Wqtl, Wkth,
                                           Wktl, Wvt, qsh, qsl, ksh, ksl);
  proj_qk8<<<dim3(256), dim3(512), 0, stream>>>(qsh, qsl, ksh, ksl, Wqth,
                                                Wqtl, Wkth, Wktl, q1hi, q1lo,
                                                k1hi, k1lo);
  qk2<<<dim3(1088), blk, 0, stream>>>(q1hi, q1lo, k1hi, k1lo, scoresA,
                                      scoresB);
  sm_projv<<<dim3(8704), blk, 0, stream>>>(scoresA, scoresB, Wvt, v, v1t);
  pv2<<<dim3(1024), blk, 0, stream>>>(scoresA, v1t, out);
}

// Round 15
// 298.087 us; speedup vs baseline: 1.1484x; 1.0119x over previous
//
#include <hip/hip_runtime.h>
#include <hip/hip_bf16.h>
#include <float.h>

// B=4, S=2048, D=1024 causal attention with input projections.
// out = softmax(mask((q@Wq)(k@Wk)^T / 32)) @ (v@Wv)
//
// Numerics: logits std ~342 -> q/k path uses bf16x2 (hi/lo RTN) split
// arithmetic, ~2^-18 effective. RTN mandatory (R2 lesson). v path bf16.
//
// R15: pv2 gets R10's proven counted-vmcnt schedule (stage tile T+1 ->
// vmcnt(6) -> barrier -> body -> barrier; 2 LDS slots = 48 KB, 3/CU) plus
// the byte^=(row&7)<<4 swizzle on both stage-source and reads (pv2's linear
// [128][64] layout had the 16-way row-stride conflict pattern R10 fixed in
// proj). Everything else = R14 (301.6us: proj 940 TF, proj_v-first merge).

typedef __attribute__((ext_vector_type(8))) short bf16x8;
typedef __attribute__((ext_vector_type(4))) float f32x4;

#define MFMA16 __builtin_amdgcn_mfma_f32_16x16x32_bf16

union U8 { bf16x8 v; unsigned w[4]; };

__device__ __forceinline__ ushort f2bf(float x) {
  union { float f; unsigned u; } v; v.f = x;
  unsigned r = v.u + 0x7fffu + ((v.u >> 16) & 1u);
  return (ushort)(r >> 16);
}
__device__ __forceinline__ float bf2f(ushort h) {
  union { unsigned u; float f; } v; v.u = ((unsigned)h) << 16;
  return v.f;
}
__device__ __forceinline__ void splitf(float x, ushort& hi, ushort& lo) {
  hi = f2bf(x);
  lo = f2bf(x - bf2f(hi));
}

__device__ __forceinline__ bf16x8 cvt8(const float* lp) {
  U8 H;
#pragma unroll
  for (int p = 0; p < 4; ++p) {
    const unsigned u0 = __float_as_uint(lp[2 * p]);
    const unsigned u1 = __float_as_uint(lp[2 * p + 1]);
    const unsigned r0 = (u0 + 0x7fffu + ((u0 >> 16) & 1u)) >> 16;
    const unsigned r1 = (u1 + 0x7fffu + ((u1 >> 16) & 1u)) & 0xffff0000u;
    H.w[p] = r0 | r1;
  }
  return H.v;
}

#define GLOAD16(gp, lp)                                                        \
  __builtin_amdgcn_global_load_lds(                                            \
      (const __attribute__((address_space(1))) void*)(gp),                     \
      (__attribute__((address_space(3))) void*)(lp), 16, 0, 0)

#define BARRIER() asm volatile("s_barrier" ::: "memory")
#define VMCNT8() asm volatile("s_waitcnt vmcnt(8)" ::: "memory")
#define VMCNT6() asm volatile("s_waitcnt vmcnt(6)" ::: "memory")
#define VMCNT0() asm volatile("s_waitcnt vmcnt(0)" ::: "memory")

// bf16 slab 128 x 32 (8 KB, 8 chunks)
__device__ __forceinline__ void stage_bf16_32(const ushort* g, int pitch,
                                              ushort* lds, int w, int lane) {
#pragma unroll
  for (int i = 0; i < 2; ++i) {
    const int c = w * 2 + i;
    const int row = c * 16 + (lane >> 2);
    const int kp = (lane & 3) * 8;
    GLOAD16(g + (size_t)row * pitch + kp, lds + c * 512);
  }
}
// fp32 slab 128 x 32 (16 KB, 16 chunks)
__device__ __forceinline__ void stage_f32_32(const float* g, int pitch,
                                             float* lds, int w, int lane) {
#pragma unroll
  for (int i = 0; i < 4; ++i) {
    const int c = w * 4 + i;
    const int row = c * 8 + (lane >> 3);
    const int kp = (lane & 7) * 4;
    GLOAD16(g + (size_t)row * pitch + kp, lds + c * 256);
  }
}

// Half-tile stage for proj_qk8: 128 rows x 64 cols bf16 (16 KB). Linear LDS
// dest; G4 swizzle byte ^= (row&7)<<4 realized by XORing the SOURCE column
// (rule #21: inverse-swz source + swz read, same involution).
__device__ __forceinline__ void stage_half8(const ushort* __restrict__ g,
                                            ushort* lds, int k0, int t) {
#pragma unroll
  for (int i = 0; i < 2; ++i) {
    const int c = t + i * 512;
    const int row = c >> 3;
    const int pcb = (c & 7) * 16;
    const int lcb = pcb ^ ((row & 7) << 4);
    GLOAD16(g + (size_t)row * 1024 + k0 + (lcb >> 1), lds + c * 8);
  }
}

// ---------------------------------------------------------------------------
// Merged prepass: f < 3072 -> W transpose+convert; f >= 3072 -> q/k split.
// ---------------------------------------------------------------------------
__global__ __launch_bounds__(256) void wt_split(
    const float* __restrict__ q, const float* __restrict__ k,
    const float* __restrict__ W0, const float* __restrict__ W1,
    const float* __restrict__ W2, ushort* __restrict__ Th0,
    ushort* __restrict__ Tl0, ushort* __restrict__ Th1,
    ushort* __restrict__ Tl1, ushort* __restrict__ Th2,
    ushort* __restrict__ qh, ushort* __restrict__ ql,
    ushort* __restrict__ kh, ushort* __restrict__ kl) {
  __shared__ float t[32][33];
  const int f = blockIdx.x;
  if (f < 3072) {
    const int z = f >> 10, r10 = f & 1023;
    const int bx = r10 & 31, by = r10 >> 5;
    const float* W = z == 0 ? W0 : (z == 1 ? W1 : W2);
    ushort* Th = z == 0 ? Th0 : (z == 1 ? Th1 : Th2);
    ushort* Tl = z == 0 ? Tl0 : (z == 1 ? Tl1 : nullptr);
    const int r = threadIdx.x >> 3, c4 = (threadIdx.x & 7) * 4;
    const float4 x = *reinterpret_cast<const float4*>(
        &W[(size_t)(bx * 32 + r) * 1024 + by * 32 + c4]);
    t[r][c4] = x.x; t[r][c4 + 1] = x.y; t[r][c4 + 2] = x.z; t[r][c4 + 3] = x.w;
    __syncthreads();
    ushort h[4], l[4];
#pragma unroll
    for (int j = 0; j < 4; ++j) splitf(t[c4 + j][r], h[j], l[j]);
    const size_t o = (size_t)(by * 32 + r) * 1024 + bx * 32 + c4;
    *reinterpret_cast<ushort4*>(&Th[o]) = ushort4{h[0], h[1], h[2], h[3]};
    if (Tl)
      *reinterpret_cast<ushort4*>(&Tl[o]) = ushort4{l[0], l[1], l[2], l[3]};
  } else {
    const int fl = f - 3072;
    const float* X = (fl >> 11) ? k : q;
    ushort* H = (fl >> 11) ? kh : qh;
    ushort* L = (fl >> 11) ? kl : ql;
    const int n4 = 2097152;
    for (int i = (fl & 2047) * 256 + threadIdx.x; i < n4; i += 2048 * 256) {
      const float4 x = reinterpret_cast<const float4*>(X)[i];
      ushort h0, l0, h1, l1, h2, l2, h3, l3;
      splitf(x.x, h0, l0); splitf(x.y, h1, l1);
      splitf(x.z, h2, l2); splitf(x.w, h3, l3);
      reinterpret_cast<ushort4*>(H)[i] = ushort4{h0, h1, h2, h3};
      reinterpret_cast<ushort4*>(L)[i] = ushort4{l0, l1, l2, l3};
    }
  }
}

// ---------------------------------------------------------------------------
// proj_qk8: O = A @ Wt^T as one bf16 GEMM, K' = 3072 segments
// [Ah.Bh | Al.Bh | Ah.Bl]. 256x256 tile, BK=64, 8 waves (2Mx4N).
// Per K-tile: stage ALL of tile T+1; vmcnt(8); barrier; body; barrier.
// 2 LDS slots (slot = kt&1, 128 KB). Grid 256, chunked XCD swizzle.
// (R10-proven: ~108us, conflicts=0, ~940 TF.)
// ---------------------------------------------------------------------------
__global__ __launch_bounds__(512, 2) void proj_qk8(
    const ushort* __restrict__ Ah0, const ushort* __restrict__ Al0,
    const ushort* __restrict__ Ah1, const ushort* __restrict__ Al1,
    const ushort* __restrict__ Bh0, const ushort* __restrict__ Bl0,
    const ushort* __restrict__ Bh1, const ushort* __restrict__ Bl1,
    ushort* __restrict__ Oh0, ushort* __restrict__ Ol0,
    ushort* __restrict__ Oh1, ushort* __restrict__ Ol1) {
  __shared__ ushort As[2][16384];  // [slot][256 rows x 64 cols], 64 KB
  __shared__ ushort Bs[2][16384];  // 64 KB
  const int bid = blockIdx.x;
  const int fid = (bid & 7) * 32 + (bid >> 3);  // 256 blocks, 8 XCDs: chunked
  const int z = fid >> 7, r = fid & 127;
  const int yt = r >> 2, xt = r & 3;
  const ushort* Ah = z ? Ah1 : Ah0;
  const ushort* Al = z ? Al1 : Al0;
  const ushort* Bh = z ? Bh1 : Bh0;
  const ushort* Bl = z ? Bl1 : Bl0;
  ushort* Oh = z ? Oh1 : Oh0;
  ushort* Ol = z ? Ol1 : Ol0;
  const size_t am0 = (size_t)yt * 256 * 1024;
  const size_t bn0 = (size_t)xt * 256 * 1024;
  const int t = threadIdx.x;
  const int lane = t & 63, w = t >> 6;
  const int wm = w >> 2, wn = w & 3;
  const int lr = lane & 15, kg = lane >> 4;
  f32x4 acc[8][4] = {};
  bf16x8 Ar[4][2], Br[4][2];

  // Stage the FULL K-tile kt (4 units = 8 loads/thread).
  auto stage_tile = [&](int kt) {
    if (kt >= 48) kt -= 48;  // wrap: harmless dummy re-stage (uniform vmcnt)
    const int seg = kt >> 4;
    const int k0 = (kt & 15) * 64;
    const int slot = kt & 1;
    const ushort* ga = (seg == 1) ? Al : Ah;
    const ushort* gb = (seg == 2) ? Bl : Bh;
#pragma unroll
    for (int h = 0; h < 2; ++h)
      stage_half8(ga + am0 + (size_t)(h * 128) * 1024, &As[slot][h * 8192], k0, t);
#pragma unroll
    for (int h = 0; h < 2; ++h)
      stage_half8(gb + bn0 + (size_t)(h * 128) * 1024, &Bs[slot][h * 8192], k0, t);
  };
  auto loadA = [&](int slot, int mq) {
#pragma unroll
    for (int m = 0; m < 4; ++m)
#pragma unroll
      for (int ks = 0; ks < 2; ++ks) {
        const int row = wm * 128 + (mq * 4 + m) * 16 + lr;
        const int cb = (ks * 64 + kg * 16) ^ ((row & 7) << 4);
        Ar[m][ks] =
            *reinterpret_cast<const bf16x8*>(&As[slot][row * 64 + (cb >> 1)]);
      }
  };
  auto loadB = [&](int slot, int nq) {
#pragma unroll
    for (int n = 0; n < 2; ++n)
#pragma unroll
      for (int ks = 0; ks < 2; ++ks) {
        const int col = wn * 64 + (nq * 2 + n) * 16 + lr;
        const int cb = (ks * 64 + kg * 16) ^ ((col & 7) << 4);
        Br[nq * 2 + n][ks] =
            *reinterpret_cast<const bf16x8*>(&Bs[slot][col * 64 + (cb >> 1)]);
      }
  };
  auto mfma_q = [&](int mq, int nq) {
    __builtin_amdgcn_s_setprio(1);
#pragma unroll
    for (int m = 0; m < 4; ++m)
#pragma unroll
      for (int n = 0; n < 2; ++n)
#pragma unroll
        for (int ks = 0; ks < 2; ++ks)
          acc[mq * 4 + m][nq * 2 + n] = MFMA16(
              Ar[m][ks], Br[nq * 2 + n][ks], acc[mq * 4 + m][nq * 2 + n], 0, 0, 0);
    __builtin_amdgcn_s_setprio(0);
  };

  // Prologue: stage K-tile 0.
  stage_tile(0);
#pragma unroll 2
  for (int kt = 0; kt < 48; ++kt) {
    const int slot = kt & 1;
    stage_tile(kt + 1);   // 8 loads -> stay in flight across both barriers
    VMCNT8();             // drain only tile kt's 8 loads
    BARRIER();
    loadA(slot, 0); loadB(slot, 0);
    mfma_q(0, 0);
    loadB(slot, 1);
    mfma_q(0, 1);
    loadA(slot, 1);
    mfma_q(1, 0);
    mfma_q(1, 1);
    BARRIER();
  }

#pragma unroll
  for (int m = 0; m < 8; ++m)
#pragma unroll
    for (int n = 0; n < 4; ++n)
#pragma unroll
      for (int reg = 0; reg < 4; ++reg) {
        const int gm = yt * 256 + wm * 128 + m * 16 + kg * 4 + reg;
        const int gn = xt * 256 + wn * 64 + n * 16 + lr;
        ushort h, l;
        splitf(acc[m][n][reg], h, l);
        Oh[(size_t)gm * 1024 + gn] = h;
        Ol[(size_t)gm * 1024 + gn] = l;
      }
}

// ---------------------------------------------------------------------------
// QK^T, bf16x2 split (3 MFMA), causal triangular grid, SPLIT-K halves.
// Flat grid 1088, chunked XCD swizzle. Packed tile output. No masking.
// ---------------------------------------------------------------------------
__global__ __launch_bounds__(256) void qk2(
    const ushort* __restrict__ q1h, const ushort* __restrict__ q1l,
    const ushort* __restrict__ k1h, const ushort* __restrict__ k1l,
    float* __restrict__ scoresA, float* __restrict__ scoresB) {
  __shared__ ushort Ahs[4096], Als[4096], Bhs[4096], Bls[4096];
  const int f = blockIdx.x;
  const int s = (f & 7) * 136 + (f >> 3);
  const int z = s / 544;
  const int rem = s % 544;
  const int b = rem / 136;
  int p = rem % 136, ti = 0, accp = 0;
  while (accp + ti + 1 <= p) { accp += ti + 1; ++ti; }
  const int tj = p - accp;
  const int tid = threadIdx.x, lane = tid & 63, w = tid >> 6;
  const int wr = w >> 1, wc = w & 1;
  const int lr = lane & 15, kg = lane >> 4;
  const int kh0 = z * 512;
  const ushort* qh = q1h + ((size_t)b * 2048 + ti * 128) * 1024 + kh0;
  const ushort* ql = q1l + ((size_t)b * 2048 + ti * 128) * 1024 + kh0;
  const ushort* kh = k1h + ((size_t)b * 2048 + tj * 128) * 1024 + kh0;
  const ushort* kl = k1l + ((size_t)b * 2048 + tj * 128) * 1024 + kh0;
  f32x4 acc[4][4] = {};

  for (int k0 = 0; k0 < 512; k0 += 32) {
    stage_bf16_32(qh + k0, 1024, Ahs, w, lane);
    stage_bf16_32(ql + k0, 1024, Als, w, lane);
    stage_bf16_32(kh + k0, 1024, Bhs, w, lane);
    stage_bf16_32(kl + k0, 1024, Bls, w, lane);
    __syncthreads();
    bf16x8 ah[4], al[4], bh[4], bl[4];
#pragma unroll
    for (int m = 0; m < 4; ++m) {
      ah[m] = *reinterpret_cast<bf16x8*>(&Ahs[(wr * 64 + m * 16 + lr) * 32 + kg * 8]);
      al[m] = *reinterpret_cast<bf16x8*>(&Als[(wr * 64 + m * 16 + lr) * 32 + kg * 8]);
    }
#pragma unroll
    for (int n = 0; n < 4; ++n) {
      bh[n] = *reinterpret_cast<bf16x8*>(&Bhs[(wc * 64 + n * 16 + lr) * 32 + kg * 8]);
      bl[n] = *reinterpret_cast<bf16x8*>(&Bls[(wc * 64 + n * 16 + lr) * 32 + kg * 8]);
    }
#pragma unroll
    for (int m = 0; m < 4; ++m)
#pragma unroll
      for (int n = 0; n < 4; ++n) {
        acc[m][n] = MFMA16(ah[m], bh[n], acc[m][n], 0, 0, 0);
        acc[m][n] = MFMA16(ah[m], bl[n], acc[m][n], 0, 0, 0);
        acc[m][n] = MFMA16(al[m], bh[n], acc[m][n], 0, 0, 0);
      }
    __syncthreads();
  }
  const float sc = 0.03125f;
  float* st = (z ? scoresB : scoresA) + ((size_t)b * 136 + p) * 16384;
#pragma unroll
  for (int m = 0; m < 4; ++m)
#pragma unroll
    for (int n = 0; n < 4; ++n)
#pragma unroll
      for (int reg = 0; reg < 4; ++reg) {
        const int il = wr * 64 + m * 16 + kg * 4 + reg;
        const int jl = wc * 64 + n * 16 + lr;
        st[il * 128 + jl] = acc[m][n][reg] * sc;
      }
}

// ---------------------------------------------------------------------------
// Merged: f < 512 -> proj_v (long GEMM blocks first, overlap softmax);
// f >= 512 -> row softmax (causal load-guard).
// ---------------------------------------------------------------------------
__global__ __launch_bounds__(256) void sm_projv(
    float* __restrict__ scoresA, const float* __restrict__ scoresB,
    const ushort* __restrict__ Wvt, const float* __restrict__ V,
    ushort* __restrict__ v1t) {
  __shared__ __align__(16) char smem[24576];
  const int tid = threadIdx.x, lane = tid & 63, w = tid >> 6;
  const int fg = blockIdx.x;
  if (fg >= 512) {
    float* red = reinterpret_cast<float*>(smem);
    const int f2 = fg - 512;
    const int b = f2 >> 11, r = f2 & 2047;
    const int ti = r >> 7, rl = r & 127, ncol = (ti + 1) * 128;
    const int valid = r + 1;
    const size_t tbase = ((size_t)b * 136 + (ti * (ti + 1)) / 2) * 16384;
    float* srowA = scoresA + tbase;
    const float* srowB = scoresB + tbase;

    float vals[2][4];
    float mx = -FLT_MAX;
#pragma unroll
    for (int c = 0; c < 2; ++c) {
      const int j = tid * 4 + c * 1024;
      if (j < ncol) {
        const size_t o = (size_t)(j >> 7) * 16384 + rl * 128 + (j & 127);
        const float4 a = *reinterpret_cast<const float4*>(srowA + o);
        const float4 bb = *reinterpret_cast<const float4*>(srowB + o);
        vals[c][0] = (j + 0 < valid) ? a.x + bb.x : -FLT_MAX;
        vals[c][1] = (j + 1 < valid) ? a.y + bb.y : -FLT_MAX;
        vals[c][2] = (j + 2 < valid) ? a.z + bb.z : -FLT_MAX;
        vals[c][3] = (j + 3 < valid) ? a.w + bb.w : -FLT_MAX;
      } else {
        vals[c][0] = vals[c][1] = vals[c][2] = vals[c][3] = -FLT_MAX;
      }
      mx = fmaxf(mx, fmaxf(fmaxf(vals[c][0], vals[c][1]),
                           fmaxf(vals[c][2], vals[c][3])));
    }
#pragma unroll
    for (int o = 32; o; o >>= 1) mx = fmaxf(mx, __shfl_xor(mx, o));
    if (lane == 0) red[w] = mx;
    __syncthreads();
    mx = fmaxf(fmaxf(red[0], red[1]), fmaxf(red[2], red[3]));

    float ex[2][4];
    float sum = 0.f;
#pragma unroll
    for (int c = 0; c < 2; ++c)
#pragma unroll
      for (int e = 0; e < 4; ++e) {
        const int j = tid * 4 + c * 1024 + e;
        ex[c][e] = (j < valid) ? __expf(vals[c][e] - mx) : 0.f;
        sum += ex[c][e];
      }
#pragma unroll
    for (int o = 32; o; o >>= 1) sum += __shfl_xor(sum, o);
    if (lane == 0) red[4 + w] = sum;
    __syncthreads();
    sum = red[4] + red[5] + red[6] + red[7];
    const float inv = 1.f / sum;
#pragma unroll
    for (int c = 0; c < 2; ++c) {
      const int j = tid * 4 + c * 1024;
      if (j < ncol) {
        ushort* pt =
            reinterpret_cast<ushort*>(srowA + (size_t)(j >> 7) * 16384);
        ushort4 pw;
        pw.x = f2bf(ex[c][0] * inv); pw.y = f2bf(ex[c][1] * inv);
        pw.z = f2bf(ex[c][2] * inv); pw.w = f2bf(ex[c][3] * inv);
        *reinterpret_cast<ushort4*>(&pt[rl * 256 + (j & 127)]) = pw;
      }
    }
  } else {
    ushort* Ahs = reinterpret_cast<ushort*>(smem);
    float* Bs = reinterpret_cast<float*>(smem + 8192);
    const int f2 = fg;
    const int yb = (f2 >> 3) & 7;
    const int xb = (f2 & 7) + ((f2 >> 6) << 3);
    const int wr = w >> 1, wc = w & 1;
    const int lr = lane & 15, kg = lane >> 4;
    const int m0 = yb * 128;
    const int n0 = xb * 128;
    f32x4 acc[4][4] = {};

    for (int k0 = 0; k0 < 1024; k0 += 32) {
      stage_bf16_32(Wvt + (size_t)m0 * 1024 + k0, 1024, Ahs, w, lane);
      stage_f32_32(V + (size_t)n0 * 1024 + k0, 1024, Bs, w, lane);
      __syncthreads();
      bf16x8 ah[4], bh[4];
#pragma unroll
      for (int m = 0; m < 4; ++m)
        ah[m] = *reinterpret_cast<bf16x8*>(
            &Ahs[(wr * 64 + m * 16 + lr) * 32 + kg * 8]);
#pragma unroll
      for (int n = 0; n < 4; ++n)
        bh[n] = cvt8(&Bs[(wc * 64 + n * 16 + lr) * 32 + kg * 8]);
#pragma unroll
      for (int m = 0; m < 4; ++m)
#pragma unroll
        for (int n = 0; n < 4; ++n)
          acc[m][n] = MFMA16(ah[m], bh[n], acc[m][n], 0, 0, 0);
      __syncthreads();
    }
#pragma unroll
    for (int m = 0; m < 4; ++m)
#pragma unroll
      for (int n = 0; n < 4; ++n)
#pragma unroll
        for (int reg = 0; reg < 4; ++reg) {
          const int gm = m0 + wr * 64 + m * 16 + kg * 4 + reg;
          const int gn = n0 + wc * 64 + n * 16 + lr;
          const int b = gn >> 11, jj = gn & 2047;
          v1t[((size_t)b << 21) + (size_t)gm * 2048 + jj] = f2bf(acc[m][n][reg]);
        }
  }
}

// ---------------------------------------------------------------------------
// PV: out = P @ v1. 128x64 tile (1024 blocks), chunked XCD swizzle.
// R15: counted-vmcnt schedule (R10 pattern) + swizzle byte^=(row&7)<<4 on
// both stage-source and reads. 2 LDS slots (48 KB -> 3 blocks/CU).
// Per K-step: stage tile T+1 (6 loads); vmcnt(6); barrier; body; barrier.
// ---------------------------------------------------------------------------
__global__ __launch_bounds__(256) void pv2(const float* __restrict__ scores,
                                           const ushort* __restrict__ v1t,
                                           float* __restrict__ out) {
  __shared__ ushort Ps[2][8192], Vs[2][4096];
  const int fl = blockIdx.x;
  const int s = (fl & 7) * 128 + (fl >> 3);
  const int b = s >> 8, rem = s & 255;
  const int ti = 15 - (rem >> 4);
  const int n0 = (rem & 15) * 64;
  const int t = threadIdx.x, lane = t & 63, w = t >> 6;
  const int wr = w >> 1, wc = w & 1;
  const int lr = lane & 15, kg = lane >> 4;
  const int tri_ti = (ti * (ti + 1)) / 2;
  const ushort* vbase = v1t + ((size_t)b << 21) + (size_t)n0 * 2048;
  const int nt = 2 * (ti + 1);  // K-steps of 64
  f32x4 acc[4][2] = {};

  // Stage K-step kt: P 128x64 (4 loads) + V 64x64 (2 loads), swizzled source.
  auto stage_tile = [&](int kt) {
    const int slot = kt & 1;
    const int k0 = kt * 64;
    const ushort* pt = reinterpret_cast<const ushort*>(
        scores + ((size_t)b * 136 + tri_ti + (k0 >> 7)) * 16384);
    const int kpo = (k0 & 64);
#pragma unroll
    for (int i = 0; i < 4; ++i) {
      const int c = t + i * 256;
      const int row = c >> 3;
      const int lcb = ((c & 7) * 16) ^ ((row & 7) << 4);
      GLOAD16(pt + (size_t)row * 256 + kpo + (lcb >> 1), Ps[slot] + c * 8);
    }
#pragma unroll
    for (int i = 0; i < 2; ++i) {
      const int c = t + i * 256;
      const int row = c >> 3;
      const int lcb = ((c & 7) * 16) ^ ((row & 7) << 4);
      GLOAD16(vbase + (size_t)row * 2048 + k0 + (lcb >> 1), Vs[slot] + c * 8);
    }
  };

  stage_tile(0);
  for (int kt = 0; kt < nt; ++kt) {
    const int slot = kt & 1;
    if (kt + 1 < nt) {
      stage_tile(kt + 1);  // 6 loads stay in flight across both barriers
      VMCNT6();
    } else {
      VMCNT0();
    }
    BARRIER();
    bf16x8 pa[4][2], vb[2][2];
#pragma unroll
    for (int m = 0; m < 4; ++m)
#pragma unroll
      for (int ks = 0; ks < 2; ++ks) {
        const int row = wr * 64 + m * 16 + lr;
        const int cb = (ks * 64 + kg * 16) ^ ((row & 7) << 4);
        pa[m][ks] =
            *reinterpret_cast<const bf16x8*>(&Ps[slot][row * 64 + (cb >> 1)]);
      }
#pragma unroll
    for (int n = 0; n < 2; ++n)
#pragma unroll
      for (int ks = 0; ks < 2; ++ks) {
        const int col = wc * 32 + n * 16 + lr;
        const int cb = (ks * 64 + kg * 16) ^ ((col & 7) << 4);
        vb[n][ks] =
            *reinterpret_cast<const bf16x8*>(&Vs[slot][col * 64 + (cb >> 1)]);
      }
    __builtin_amdgcn_s_setprio(1);
#pragma unroll
    for (int m = 0; m < 4; ++m)
#pragma unroll
      for (int n = 0; n < 2; ++n)
#pragma unroll
        for (int ks = 0; ks < 2; ++ks)
          acc[m][n] = MFMA16(pa[m][ks], vb[n][ks], acc[m][n], 0, 0, 0);
    __builtin_amdgcn_s_setprio(0);
    BARRIER();
  }
#pragma unroll
  for (int m = 0; m < 4; ++m)
#pragma unroll
    for (int n = 0; n < 2; ++n)
#pragma unroll
      for (int reg = 0; reg < 4; ++reg) {
        const int gm = ti * 128 + wr * 64 + m * 16 + kg * 4 + reg;
        const int gn = n0 + wc * 32 + n * 16 + lr;
        out[((size_t)b * 2048 + gm) * 1024 + gn] = acc[m][n][reg];
      }
}

extern "C" void kernel_launch(void* const* d_in, const int* in_sizes, int n_in,
                              void* d_out, int out_size, void* d_ws,
                              size_t ws_size, hipStream_t stream) {
  const float* q = (const float*)d_in[0];
  const float* k = (const float*)d_in[1];
  const float* v = (const float*)d_in[2];
  const float* Wq = (const float*)d_in[4];
  const float* Wk = (const float*)d_in[5];
  const float* Wv = (const float*)d_in[6];
  float* out = (float*)d_out;

  char* ws = (char*)d_ws;
  const size_t SCORES_T = 35651584;  // 4*136*16384*4
  float* scoresA = (float*)ws;
  float* scoresB = (float*)(ws + SCORES_T);
  ushort* qsh = (ushort*)ws;
  ushort* qsl = qsh + 8388608;
  ushort* ksh = qsh + 2 * 8388608;
  ushort* ksl = qsh + 3 * 8388608;
  ushort* q1hi = (ushort*)(ws + 2 * SCORES_T);
  ushort* q1lo = q1hi + 8388608;
  ushort* k1hi = q1hi + 2 * 8388608;
  ushort* k1lo = q1hi + 3 * 8388608;
  ushort* v1t = (ushort*)(ws + 2 * SCORES_T);
  ushort* Wqth = (ushort*)(ws + 2 * SCORES_T + 67108864);
  ushort* Wqtl = Wqth + 1048576;
  ushort* Wkth = Wqth + 2097152;
  ushort* Wktl = Wqth + 3145728;
  ushort* Wvt  = Wqth + 4194304;
  const size_t need = 2 * SCORES_T + 67108864 + 10485760;
  if (ws_size < need) return;

  dim3 blk(256);
  wt_split<<<dim3(7168), blk, 0, stream>>>(q, k, Wq, Wk, Wv, Wqth, Wqtl, Wkth,
                                           Wktl, Wvt, qsh, qsl, ksh, ksl);
  proj_qk8<<<dim3(256), dim3(512), 0, stream>>>(qsh, qsl, ksh, ksl, Wqth,
                                                Wqtl, Wkth, Wktl, q1hi, q1lo,
                                                k1hi, k1lo);
  qk2<<<dim3(1088), blk, 0, stream>>>(q1hi, q1lo, k1hi, k1lo, scoresA,
                                      scoresB);
  sm_projv<<<dim3(8704), blk, 0, stream>>>(scoresA, scoresB, Wvt, v, v1t);
  pv2<<<dim3(1024), blk, 0, stream>>>(scoresA, v1t, out);
}

// Round 16
// 289.284 us; speedup vs baseline: 1.1833x; 1.0304x over previous
//
#include <hip/hip_runtime.h>
#include <hip/hip_bf16.h>
#include <float.h>

// B=4, S=2048, D=1024 causal attention with input projections.
// out = softmax(mask((q@Wq)(k@Wk)^T / 32)) @ (v@Wv)
//
// Numerics: logits std ~342 -> q/k path uses bf16x2 (hi/lo RTN) split
// arithmetic, ~2^-18 effective. RTN mandatory (R2 lesson). v path bf16.
//
// R16: proj + qk rebuilt as 4-SLAB 3-MFMA loops (Ah,Al,Bh,Bl live in LDS
// simultaneously; register fragments reused across the 3 products) with
// R10's proven counted-vmcnt skeleton. Eliminates the K'=3N concatenation's
// 1.5x staging + ds_read redundancy: per 64-K, staged bytes 96->64 KB and
// ds_reads 36->24/thread at identical MFMA count; fewer barriers too.
// Swizzle for 64B-pitch slabs: byte ^= ((row>>1)&3)<<4 both sides (2-way
// residual = free). proj: 256^2 tile, BK=32, 128 KB LDS. qk: 128^2, BK=32,
// 64 KB LDS. pv2/sm_projv/wt_split frozen from R15 (298.1us).

typedef __attribute__((ext_vector_type(8))) short bf16x8;
typedef __attribute__((ext_vector_type(4))) float f32x4;

#define MFMA16 __builtin_amdgcn_mfma_f32_16x16x32_bf16

union U8 { bf16x8 v; unsigned w[4]; };

__device__ __forceinline__ ushort f2bf(float x) {
  union { float f; unsigned u; } v; v.f = x;
  unsigned r = v.u + 0x7fffu + ((v.u >> 16) & 1u);
  return (ushort)(r >> 16);
}
__device__ __forceinline__ float bf2f(ushort h) {
  union { unsigned u; float f; } v; v.u = ((unsigned)h) << 16;
  return v.f;
}
__device__ __forceinline__ void splitf(float x, ushort& hi, ushort& lo) {
  hi = f2bf(x);
  lo = f2bf(x - bf2f(hi));
}

__device__ __forceinline__ bf16x8 cvt8(const float* lp) {
  U8 H;
#pragma unroll
  for (int p = 0; p < 4; ++p) {
    const unsigned u0 = __float_as_uint(lp[2 * p]);
    const unsigned u1 = __float_as_uint(lp[2 * p + 1]);
    const unsigned r0 = (u0 + 0x7fffu + ((u0 >> 16) & 1u)) >> 16;
    const unsigned r1 = (u1 + 0x7fffu + ((u1 >> 16) & 1u)) & 0xffff0000u;
    H.w[p] = r0 | r1;
  }
  return H.v;
}

#define GLOAD16(gp, lp)                                                        \
  __builtin_amdgcn_global_load_lds(                                            \
      (const __attribute__((address_space(1))) void*)(gp),                     \
      (__attribute__((address_space(3))) void*)(lp), 16, 0, 0)

#define BARRIER() asm volatile("s_barrier" ::: "memory")
#define VMCNT8() asm volatile("s_waitcnt vmcnt(8)" ::: "memory")
#define VMCNT6() asm volatile("s_waitcnt vmcnt(6)" ::: "memory")
#define VMCNT0() asm volatile("s_waitcnt vmcnt(0)" ::: "memory")

// bf16 slab 128 x 32 (8 KB, 8 chunks) — sm_projv staging
__device__ __forceinline__ void stage_bf16_32(const ushort* g, int pitch,
                                              ushort* lds, int w, int lane) {
#pragma unroll
  for (int i = 0; i < 2; ++i) {
    const int c = w * 2 + i;
    const int row = c * 16 + (lane >> 2);
    const int kp = (lane & 3) * 8;
    GLOAD16(g + (size_t)row * pitch + kp, lds + c * 512);
  }
}
// fp32 slab 128 x 32 (16 KB, 16 chunks)
__device__ __forceinline__ void stage_f32_32(const float* g, int pitch,
                                             float* lds, int w, int lane) {
#pragma unroll
  for (int i = 0; i < 4; ++i) {
    const int c = w * 4 + i;
    const int row = c * 8 + (lane >> 3);
    const int kp = (lane & 7) * 4;
    GLOAD16(g + (size_t)row * pitch + kp, lds + c * 256);
  }
}

// Swizzled fragment read from a [rows][32] bf16 slab (64 B row pitch):
// logical (row, byte kg*16) lives at byte ^ ((row>>1)&3)<<4.
__device__ __forceinline__ bf16x8 rd32(const ushort* s, int row, int kg) {
  const int cb = (kg * 16) ^ (((row >> 1) & 3) << 4);
  return *reinterpret_cast<const bf16x8*>(&s[row * 32 + (cb >> 1)]);
}

// ---------------------------------------------------------------------------
// Merged prepass: f < 3072 -> W transpose+convert; f >= 3072 -> q/k split.
// ---------------------------------------------------------------------------
__global__ __launch_bounds__(256) void wt_split(
    const float* __restrict__ q, const float* __restrict__ k,
    const float* __restrict__ W0, const float* __restrict__ W1,
    const float* __restrict__ W2, ushort* __restrict__ Th0,
    ushort* __restrict__ Tl0, ushort* __restrict__ Th1,
    ushort* __restrict__ Tl1, ushort* __restrict__ Th2,
    ushort* __restrict__ qh, ushort* __restrict__ ql,
    ushort* __restrict__ kh, ushort* __restrict__ kl) {
  __shared__ float t[32][33];
  const int f = blockIdx.x;
  if (f < 3072) {
    const int z = f >> 10, r10 = f & 1023;
    const int bx = r10 & 31, by = r10 >> 5;
    const float* W = z == 0 ? W0 : (z == 1 ? W1 : W2);
    ushort* Th = z == 0 ? Th0 : (z == 1 ? Th1 : Th2);
    ushort* Tl = z == 0 ? Tl0 : (z == 1 ? Tl1 : nullptr);
    const int r = threadIdx.x >> 3, c4 = (threadIdx.x & 7) * 4;
    const float4 x = *reinterpret_cast<const float4*>(
        &W[(size_t)(bx * 32 + r) * 1024 + by * 32 + c4]);
    t[r][c4] = x.x; t[r][c4 + 1] = x.y; t[r][c4 + 2] = x.z; t[r][c4 + 3] = x.w;
    __syncthreads();
    ushort h[4], l[4];
#pragma unroll
    for (int j = 0; j < 4; ++j) splitf(t[c4 + j][r], h[j], l[j]);
    const size_t o = (size_t)(by * 32 + r) * 1024 + bx * 32 + c4;
    *reinterpret_cast<ushort4*>(&Th[o]) = ushort4{h[0], h[1], h[2], h[3]};
    if (Tl)
      *reinterpret_cast<ushort4*>(&Tl[o]) = ushort4{l[0], l[1], l[2], l[3]};
  } else {
    const int fl = f - 3072;
    const float* X = (fl >> 11) ? k : q;
    ushort* H = (fl >> 11) ? kh : qh;
    ushort* L = (fl >> 11) ? kl : ql;
    const int n4 = 2097152;
    for (int i = (fl & 2047) * 256 + threadIdx.x; i < n4; i += 2048 * 256) {
      const float4 x = reinterpret_cast<const float4*>(X)[i];
      ushort h0, l0, h1, l1, h2, l2, h3, l3;
      splitf(x.x, h0, l0); splitf(x.y, h1, l1);
      splitf(x.z, h2, l2); splitf(x.w, h3, l3);
      reinterpret_cast<ushort4*>(H)[i] = ushort4{h0, h1, h2, h3};
      reinterpret_cast<ushort4*>(L)[i] = ushort4{l0, l1, l2, l3};
    }
  }
}

// ---------------------------------------------------------------------------
// proj_qk8: q1/k1 = [q|k] @ Wt^T, 4-slab 3-MFMA form. 256x256 tile, BK=32,
// 8 waves (2Mx4N). Per step: stage all 4 slabs of step T+1 (8 loads);
// vmcnt(8); barrier; 24 swizzled ds_read + 96 MFMA; barrier.
// LDS = 4 slabs x 2 slots x 16 KB = 128 KB. Grid 256, chunked XCD swizzle.
// ---------------------------------------------------------------------------
__global__ __launch_bounds__(512, 2) void proj_qk8(
    const ushort* __restrict__ Ah0, const ushort* __restrict__ Al0,
    const ushort* __restrict__ Ah1, const ushort* __restrict__ Al1,
    const ushort* __restrict__ Bh0, const ushort* __restrict__ Bl0,
    const ushort* __restrict__ Bh1, const ushort* __restrict__ Bl1,
    ushort* __restrict__ Oh0, ushort* __restrict__ Ol0,
    ushort* __restrict__ Oh1, ushort* __restrict__ Ol1) {
  __shared__ ushort Ahs[2][8192], Als[2][8192];  // 256x32 each, 16 KB
  __shared__ ushort Bhs[2][8192], Bls[2][8192];
  const int bid = blockIdx.x;
  const int fid = (bid & 7) * 32 + (bid >> 3);  // chunked over 8 XCDs
  const int z = fid >> 7, r = fid & 127;
  const int yt = r >> 2, xt = r & 3;
  const ushort* Ahp = (z ? Ah1 : Ah0) + (size_t)yt * 256 * 1024;
  const ushort* Alp = (z ? Al1 : Al0) + (size_t)yt * 256 * 1024;
  const ushort* Bhp = (z ? Bh1 : Bh0) + (size_t)xt * 256 * 1024;
  const ushort* Blp = (z ? Bl1 : Bl0) + (size_t)xt * 256 * 1024;
  ushort* Oh = z ? Oh1 : Oh0;
  ushort* Ol = z ? Ol1 : Ol0;
  const int t = threadIdx.x;
  const int lane = t & 63, w = t >> 6;
  const int wm = w >> 2, wn = w & 3;
  const int lr = lane & 15, kg = lane >> 4;
  f32x4 acc[8][4] = {};

  // Stage one 256x32 slab (1024 chunks of 16B, 2/thread), swizzled source.
  auto stage_slab = [&](const ushort* g, ushort* lds, int k0) {
#pragma unroll
    for (int i = 0; i < 2; ++i) {
      const int c = t + i * 512;
      const int row = c >> 2;
      const int lcb = ((c & 3) * 16) ^ (((row >> 1) & 3) << 4);
      GLOAD16(g + (size_t)row * 1024 + k0 + (lcb >> 1), lds + c * 8);
    }
  };
  auto stage_tile = [&](int kt) {
    const int k0 = kt * 32;
    const int slot = kt & 1;
    stage_slab(Ahp, Ahs[slot], k0);
    stage_slab(Alp, Als[slot], k0);
    stage_slab(Bhp, Bhs[slot], k0);
    stage_slab(Blp, Bls[slot], k0);
  };

  stage_tile(0);
  for (int kt = 0; kt < 32; ++kt) {
    const int slot = kt & 1;
    if (kt + 1 < 32) {
      stage_tile(kt + 1);  // 8 loads stay in flight across both barriers
      VMCNT8();            // step kt's 8 loads landed
    } else {
      VMCNT0();
    }
    BARRIER();
    bf16x8 bh[4], bl[4];
#pragma unroll
    for (int n = 0; n < 4; ++n) {
      const int col = wn * 64 + n * 16 + lr;
      bh[n] = rd32(Bhs[slot], col, kg);
      bl[n] = rd32(Bls[slot], col, kg);
    }
#pragma unroll
    for (int mq = 0; mq < 2; ++mq) {
      bf16x8 ah[4], al[4];
#pragma unroll
      for (int m = 0; m < 4; ++m) {
        const int row = wm * 128 + (mq * 4 + m) * 16 + lr;
        ah[m] = rd32(Ahs[slot], row, kg);
        al[m] = rd32(Als[slot], row, kg);
      }
      __builtin_amdgcn_s_setprio(1);
#pragma unroll
      for (int m = 0; m < 4; ++m)
#pragma unroll
        for (int n = 0; n < 4; ++n) {
          acc[mq * 4 + m][n] = MFMA16(ah[m], bh[n], acc[mq * 4 + m][n], 0, 0, 0);
          acc[mq * 4 + m][n] = MFMA16(ah[m], bl[n], acc[mq * 4 + m][n], 0, 0, 0);
          acc[mq * 4 + m][n] = MFMA16(al[m], bh[n], acc[mq * 4 + m][n], 0, 0, 0);
        }
      __builtin_amdgcn_s_setprio(0);
    }
    BARRIER();
  }

#pragma unroll
  for (int m = 0; m < 8; ++m)
#pragma unroll
    for (int n = 0; n < 4; ++n)
#pragma unroll
      for (int reg = 0; reg < 4; ++reg) {
        const int gm = yt * 256 + wm * 128 + m * 16 + kg * 4 + reg;
        const int gn = xt * 256 + wn * 64 + n * 16 + lr;
        ushort h, l;
        splitf(acc[m][n][reg], h, l);
        Oh[(size_t)gm * 1024 + gn] = h;
        Ol[(size_t)gm * 1024 + gn] = l;
      }
}

// ---------------------------------------------------------------------------
// QK^T, 4-slab 3-MFMA, counted-vmcnt. 128x128 tile, BK=32, 4 waves (2x2),
// split-K halves (K=512 -> 16 steps). LDS = 4 x 2 x 8 KB = 64 KB.
// Flat grid 1088, chunked XCD swizzle. Packed tile output. No masking.
// ---------------------------------------------------------------------------
__global__ __launch_bounds__(256) void qk2(
    const ushort* __restrict__ q1h, const ushort* __restrict__ q1l,
    const ushort* __restrict__ k1h, const ushort* __restrict__ k1l,
    float* __restrict__ scoresA, float* __restrict__ scoresB) {
  __shared__ ushort Ahs[2][4096], Als[2][4096];  // 128x32 each, 8 KB
  __shared__ ushort Bhs[2][4096], Bls[2][4096];
  const int f = blockIdx.x;
  const int s = (f & 7) * 136 + (f >> 3);
  const int z = s / 544;
  const int rem = s % 544;
  const int b = rem / 136;
  int p = rem % 136, ti = 0, accp = 0;
  while (accp + ti + 1 <= p) { accp += ti + 1; ++ti; }
  const int tj = p - accp;
  const int t = threadIdx.x, lane = t & 63, w = t >> 6;
  const int wr = w >> 1, wc = w & 1;
  const int lr = lane & 15, kg = lane >> 4;
  const int kh0 = z * 512;
  const ushort* qh = q1h + ((size_t)b * 2048 + ti * 128) * 1024 + kh0;
  const ushort* ql = q1l + ((size_t)b * 2048 + ti * 128) * 1024 + kh0;
  const ushort* kh = k1h + ((size_t)b * 2048 + tj * 128) * 1024 + kh0;
  const ushort* kl = k1l + ((size_t)b * 2048 + tj * 128) * 1024 + kh0;
  f32x4 acc[4][4] = {};

  // Stage one 128x32 slab (512 chunks, 2/thread), swizzled source.
  auto stage_slab = [&](const ushort* g, ushort* lds, int k0) {
#pragma unroll
    for (int i = 0; i < 2; ++i) {
      const int c = t + i * 256;
      const int row = c >> 2;
      const int lcb = ((c & 3) * 16) ^ (((row >> 1) & 3) << 4);
      GLOAD16(g + (size_t)row * 1024 + k0 + (lcb >> 1), lds + c * 8);
    }
  };
  auto stage_tile = [&](int kt) {
    const int k0 = kt * 32;
    const int slot = kt & 1;
    stage_slab(qh, Ahs[slot], k0);
    stage_slab(ql, Als[slot], k0);
    stage_slab(kh, Bhs[slot], k0);
    stage_slab(kl, Bls[slot], k0);
  };

  stage_tile(0);
  for (int kt = 0; kt < 16; ++kt) {
    const int slot = kt & 1;
    if (kt + 1 < 16) {
      stage_tile(kt + 1);
      VMCNT8();
    } else {
      VMCNT0();
    }
    BARRIER();
    bf16x8 ah[4], al[4], bh[4], bl[4];
#pragma unroll
    for (int m = 0; m < 4; ++m) {
      const int row = wr * 64 + m * 16 + lr;
      ah[m] = rd32(Ahs[slot], row, kg);
      al[m] = rd32(Als[slot], row, kg);
    }
#pragma unroll
    for (int n = 0; n < 4; ++n) {
      const int col = wc * 64 + n * 16 + lr;
      bh[n] = rd32(Bhs[slot], col, kg);
      bl[n] = rd32(Bls[slot], col, kg);
    }
    __builtin_amdgcn_s_setprio(1);
#pragma unroll
    for (int m = 0; m < 4; ++m)
#pragma unroll
      for (int n = 0; n < 4; ++n) {
        acc[m][n] = MFMA16(ah[m], bh[n], acc[m][n], 0, 0, 0);
        acc[m][n] = MFMA16(ah[m], bl[n], acc[m][n], 0, 0, 0);
        acc[m][n] = MFMA16(al[m], bh[n], acc[m][n], 0, 0, 0);
      }
    __builtin_amdgcn_s_setprio(0);
    BARRIER();
  }
  const float sc = 0.03125f;
  float* st = (z ? scoresB : scoresA) + ((size_t)b * 136 + p) * 16384;
#pragma unroll
  for (int m = 0; m < 4; ++m)
#pragma unroll
    for (int n = 0; n < 4; ++n)
#pragma unroll
      for (int reg = 0; reg < 4; ++reg) {
        const int il = wr * 64 + m * 16 + kg * 4 + reg;
        const int jl = wc * 64 + n * 16 + lr;
        st[il * 128 + jl] = acc[m][n][reg] * sc;
      }
}

// ---------------------------------------------------------------------------
// Merged: f < 512 -> proj_v (long GEMM blocks first, overlap softmax);
// f >= 512 -> row softmax (causal load-guard).
// ---------------------------------------------------------------------------
__global__ __launch_bounds__(256) void sm_projv(
    float* __restrict__ scoresA, const float* __restrict__ scoresB,
    const ushort* __restrict__ Wvt, const float* __restrict__ V,
    ushort* __restrict__ v1t) {
  __shared__ __align__(16) char smem[24576];
  const int tid = threadIdx.x, lane = tid & 63, w = tid >> 6;
  const int fg = blockIdx.x;
  if (fg >= 512) {
    float* red = reinterpret_cast<float*>(smem);
    const int f2 = fg - 512;
    const int b = f2 >> 11, r = f2 & 2047;
    const int ti = r >> 7, rl = r & 127, ncol = (ti + 1) * 128;
    const int valid = r + 1;
    const size_t tbase = ((size_t)b * 136 + (ti * (ti + 1)) / 2) * 16384;
    float* srowA = scoresA + tbase;
    const float* srowB = scoresB + tbase;

    float vals[2][4];
    float mx = -FLT_MAX;
#pragma unroll
    for (int c = 0; c < 2; ++c) {
      const int j = tid * 4 + c * 1024;
      if (j < ncol) {
        const size_t o = (size_t)(j >> 7) * 16384 + rl * 128 + (j & 127);
        const float4 a = *reinterpret_cast<const float4*>(srowA + o);
        const float4 bb = *reinterpret_cast<const float4*>(srowB + o);
        vals[c][0] = (j + 0 < valid) ? a.x + bb.x : -FLT_MAX;
        vals[c][1] = (j + 1 < valid) ? a.y + bb.y : -FLT_MAX;
        vals[c][2] = (j + 2 < valid) ? a.z + bb.z : -FLT_MAX;
        vals[c][3] = (j + 3 < valid) ? a.w + bb.w : -FLT_MAX;
      } else {
        vals[c][0] = vals[c][1] = vals[c][2] = vals[c][3] = -FLT_MAX;
      }
      mx = fmaxf(mx, fmaxf(fmaxf(vals[c][0], vals[c][1]),
                           fmaxf(vals[c][2], vals[c][3])));
    }
#pragma unroll
    for (int o = 32; o; o >>= 1) mx = fmaxf(mx, __shfl_xor(mx, o));
    if (lane == 0) red[w] = mx;
    __syncthreads();
    mx = fmaxf(fmaxf(red[0], red[1]), fmaxf(red[2], red[3]));

    float ex[2][4];
    float sum = 0.f;
#pragma unroll
    for (int c = 0; c < 2; ++c)
#pragma unroll
      for (int e = 0; e < 4; ++e) {
        const int j = tid * 4 + c * 1024 + e;
        ex[c][e] = (j < valid) ? __expf(vals[c][e] - mx) : 0.f;
        sum += ex[c][e];
      }
#pragma unroll
    for (int o = 32; o; o >>= 1) sum += __shfl_xor(sum, o);
    if (lane == 0) red[4 + w] = sum;
    __syncthreads();
    sum = red[4] + red[5] + red[6] + red[7];
    const float inv = 1.f / sum;
#pragma unroll
    for (int c = 0; c < 2; ++c) {
      const int j = tid * 4 + c * 1024;
      if (j < ncol) {
        ushort* pt =
            reinterpret_cast<ushort*>(srowA + (size_t)(j >> 7) * 16384);
        ushort4 pw;
        pw.x = f2bf(ex[c][0] * inv); pw.y = f2bf(ex[c][1] * inv);
        pw.z = f2bf(ex[c][2] * inv); pw.w = f2bf(ex[c][3] * inv);
        *reinterpret_cast<ushort4*>(&pt[rl * 256 + (j & 127)]) = pw;
      }
    }
  } else {
    ushort* Ahs = reinterpret_cast<ushort*>(smem);
    float* Bs = reinterpret_cast<float*>(smem + 8192);
    const int f2 = fg;
    const int yb = (f2 >> 3) & 7;
    const int xb = (f2 & 7) + ((f2 >> 6) << 3);
    const int wr = w >> 1, wc = w & 1;
    const int lr = lane & 15, kg = lane >> 4;
    const int m0 = yb * 128;
    const int n0 = xb * 128;
    f32x4 acc[4][4] = {};

    for (int k0 = 0; k0 < 1024; k0 += 32) {
      stage_bf16_32(Wvt + (size_t)m0 * 1024 + k0, 1024, Ahs, w, lane);
      stage_f32_32(V + (size_t)n0 * 1024 + k0, 1024, Bs, w, lane);
      __syncthreads();
      bf16x8 ah[4], bh[4];
#pragma unroll
      for (int m = 0; m < 4; ++m)
        ah[m] = *reinterpret_cast<bf16x8*>(
            &Ahs[(wr * 64 + m * 16 + lr) * 32 + kg * 8]);
#pragma unroll
      for (int n = 0; n < 4; ++n)
        bh[n] = cvt8(&Bs[(wc * 64 + n * 16 + lr) * 32 + kg * 8]);
#pragma unroll
      for (int m = 0; m < 4; ++m)
#pragma unroll
        for (int n = 0; n < 4; ++n)
          acc[m][n] = MFMA16(ah[m], bh[n], acc[m][n], 0, 0, 0);
      __syncthreads();
    }
#pragma unroll
    for (int m = 0; m < 4; ++m)
#pragma unroll
      for (int n = 0; n < 4; ++n)
#pragma unroll
        for (int reg = 0; reg < 4; ++reg) {
          const int gm = m0 + wr * 64 + m * 16 + kg * 4 + reg;
          const int gn = n0 + wc * 64 + n * 16 + lr;
          const int b = gn >> 11, jj = gn & 2047;
          v1t[((size_t)b << 21) + (size_t)gm * 2048 + jj] = f2bf(acc[m][n][reg]);
        }
  }
}

// ---------------------------------------------------------------------------
// PV: out = P @ v1. 128x64 tile (1024 blocks), chunked XCD swizzle.
// Counted-vmcnt (R15): stage tile T+1 (6 loads); vmcnt(6); barrier; body;
// barrier. Swizzle byte^=(row&7)<<4 both sides (128B-pitch slabs).
// ---------------------------------------------------------------------------
__global__ __launch_bounds__(256) void pv2(const float* __restrict__ scores,
                                           const ushort* __restrict__ v1t,
                                           float* __restrict__ out) {
  __shared__ ushort Ps[2][8192], Vs[2][4096];
  const int fl = blockIdx.x;
  const int s = (fl & 7) * 128 + (fl >> 3);
  const int b = s >> 8, rem = s & 255;
  const int ti = 15 - (rem >> 4);
  const int n0 = (rem & 15) * 64;
  const int t = threadIdx.x, lane = t & 63, w = t >> 6;
  const int wr = w >> 1, wc = w & 1;
  const int lr = lane & 15, kg = lane >> 4;
  const int tri_ti = (ti * (ti + 1)) / 2;
  const ushort* vbase = v1t + ((size_t)b << 21) + (size_t)n0 * 2048;
  const int nt = 2 * (ti + 1);  // K-steps of 64
  f32x4 acc[4][2] = {};

  auto stage_tile = [&](int kt) {
    const int slot = kt & 1;
    const int k0 = kt * 64;
    const ushort* pt = reinterpret_cast<const ushort*>(
        scores + ((size_t)b * 136 + tri_ti + (k0 >> 7)) * 16384);
    const int kpo = (k0 & 64);
#pragma unroll
    for (int i = 0; i < 4; ++i) {
      const int c = t + i * 256;
      const int row = c >> 3;
      const int lcb = ((c & 7) * 16) ^ ((row & 7) << 4);
      GLOAD16(pt + (size_t)row * 256 + kpo + (lcb >> 1), Ps[slot] + c * 8);
    }
#pragma unroll
    for (int i = 0; i < 2; ++i) {
      const int c = t + i * 256;
      const int row = c >> 3;
      const int lcb = ((c & 7) * 16) ^ ((row & 7) << 4);
      GLOAD16(vbase + (size_t)row * 2048 + k0 + (lcb >> 1), Vs[slot] + c * 8);
    }
  };

  stage_tile(0);
  for (int kt = 0; kt < nt; ++kt) {
    const int slot = kt & 1;
    if (kt + 1 < nt) {
      stage_tile(kt + 1);
      VMCNT6();
    } else {
      VMCNT0();
    }
    BARRIER();
    bf16x8 pa[4][2], vb[2][2];
#pragma unroll
    for (int m = 0; m < 4; ++m)
#pragma unroll
      for (int ks = 0; ks < 2; ++ks) {
        const int row = wr * 64 + m * 16 + lr;
        const int cb = (ks * 64 + kg * 16) ^ ((row & 7) << 4);
        pa[m][ks] =
            *reinterpret_cast<const bf16x8*>(&Ps[slot][row * 64 + (cb >> 1)]);
      }
#pragma unroll
    for (int n = 0; n < 2; ++n)
#pragma unroll
      for (int ks = 0; ks < 2; ++ks) {
        const int col = wc * 32 + n * 16 + lr;
        const int cb = (ks * 64 + kg * 16) ^ ((col & 7) << 4);
        vb[n][ks] =
            *reinterpret_cast<const bf16x8*>(&Vs[slot][col * 64 + (cb >> 1)]);
      }
    __builtin_amdgcn_s_setprio(1);
#pragma unroll
    for (int m = 0; m < 4; ++m)
#pragma unroll
      for (int n = 0; n < 2; ++n)
#pragma unroll
        for (int ks = 0; ks < 2; ++ks)
          acc[m][n] = MFMA16(pa[m][ks], vb[n][ks], acc[m][n], 0, 0, 0);
    __builtin_amdgcn_s_setprio(0);
    BARRIER();
  }
#pragma unroll
  for (int m = 0; m < 4; ++m)
#pragma unroll
    for (int n = 0; n < 2; ++n)
#pragma unroll
      for (int reg = 0; reg < 4; ++reg) {
        const int gm = ti * 128 + wr * 64 + m * 16 + kg * 4 + reg;
        const int gn = n0 + wc * 32 + n * 16 + lr;
        out[((size_t)b * 2048 + gm) * 1024 + gn] = acc[m][n][reg];
      }
}

extern "C" void kernel_launch(void* const* d_in, const int* in_sizes, int n_in,
                              void* d_out, int out_size, void* d_ws,
                              size_t ws_size, hipStream_t stream) {
  const float* q = (const float*)d_in[0];
  const float* k = (const float*)d_in[1];
  const float* v = (const float*)d_in[2];
  const float* Wq = (const float*)d_in[4];
  const float* Wk = (const float*)d_in[5];
  const float* Wv = (const float*)d_in[6];
  float* out = (float*)d_out;

  char* ws = (char*)d_ws;
  const size_t SCORES_T = 35651584;  // 4*136*16384*4
  float* scoresA = (float*)ws;
  float* scoresB = (float*)(ws + SCORES_T);
  ushort* qsh = (ushort*)ws;
  ushort* qsl = qsh + 8388608;
  ushort* ksh = qsh + 2 * 8388608;
  ushort* ksl = qsh + 3 * 8388608;
  ushort* q1hi = (ushort*)(ws + 2 * SCORES_T);
  ushort* q1lo = q1hi + 8388608;
  ushort* k1hi = q1hi + 2 * 8388608;
  ushort* k1lo = q1hi + 3 * 8388608;
  ushort* v1t = (ushort*)(ws + 2 * SCORES_T);
  ushort* Wqth = (ushort*)(ws + 2 * SCORES_T + 67108864);
  ushort* Wqtl = Wqth + 1048576;
  ushort* Wkth = Wqth + 2097152;
  ushort* Wktl = Wqth + 3145728;
  ushort* Wvt  = Wqth + 4194304;
  const size_t need = 2 * SCORES_T + 67108864 + 10485760;
  if (ws_size < need) return;

  dim3 blk(256);
  wt_split<<<dim3(7168), blk, 0, stream>>>(q, k, Wq, Wk, Wv, Wqth, Wqtl, Wkth,
                                           Wktl, Wvt, qsh, qsl, ksh, ksl);
  proj_qk8<<<dim3(256), dim3(512), 0, stream>>>(qsh, qsl, ksh, ksl, Wqth,
                                                Wqtl, Wkth, Wktl, q1hi, q1lo,
                                                k1hi, k1lo);
  qk2<<<dim3(1088), blk, 0, stream>>>(q1hi, q1lo, k1hi, k1lo, scoresA,
                                      scoresB);
  sm_projv<<<dim3(8704), blk, 0, stream>>>(scoresA, scoresB, Wvt, v, v1t);
  pv2<<<dim3(1024), blk, 0, stream>>>(scoresA, v1t, out);
}